// Round 5
// baseline (246.129 us; speedup 1.0000x reference)
//
#include <hip/hip_runtime.h>

// ---- problem constants ----
#define L_DIM 197
#define N_DIM 256
#define C_DIM 768
#define CA_DIM 192
#define M_DIM (L_DIM * N_DIM)   // 50432

typedef short s16x8 __attribute__((ext_vector_type(8)));
typedef float f32x4 __attribute__((ext_vector_type(4)));

__device__ __forceinline__ unsigned short f2bf(float f) {
  unsigned x = __builtin_bit_cast(unsigned, f);
  x = (x + 0x7fffu + ((x >> 16) & 1u)) >> 16;   // RNE
  return (unsigned short)x;
}
__device__ __forceinline__ float bflo(unsigned u) { return __builtin_bit_cast(float, u << 16); }
__device__ __forceinline__ float bfhi(unsigned u) { return __builtin_bit_cast(float, u & 0xffff0000u); }

__device__ __forceinline__ void unp8(uint4 v, float* f) {
  f[0] = bflo(v.x); f[1] = bfhi(v.x); f[2] = bflo(v.y); f[3] = bfhi(v.y);
  f[4] = bflo(v.z); f[5] = bfhi(v.z); f[6] = bflo(v.w); f[7] = bfhi(v.w);
}

__device__ __forceinline__ void mfma16(f32x4& acc, s16x8 a, s16x8 b) {
  asm("v_mfma_f32_16x16x32_bf16 %0, %1, %2, %0" : "+v"(acc) : "v"(a), "v"(b));
}

// async global->LDS 16B
typedef const void __attribute__((address_space(1)))* gp_t;
typedef void __attribute__((address_space(3)))* lp_t;
__device__ __forceinline__ void gl16(const void* g, void* l) {
  __builtin_amdgcn_global_load_lds((gp_t)g, (lp_t)l, 16, 0, 0);
}

// bijective XCD-chunk swizzle (m204)
__device__ __forceinline__ int swz(int pid, int nwg) {
  const int q = nwg >> 3, r = nwg & 7, x = pid & 7, s = pid >> 3;
  return (x < r ? x * (q + 1) : r * (q + 1) + (x - r) * q) + s;
}

// LDS bank swizzle for 128B-row tiles: elem index of (row, byte-col) with
// byte-col XOR'd by (row&7)<<4  ->  lanes fr=0..15 spread over 8 bank-quads.
__device__ __forceinline__ int lidx(int row, int colb) {
  return (row * 128 + (colb ^ ((row & 7) << 4))) >> 1;
}

// ---------------------------------------------------------------------------
// prep: LDS-tiled transpose + fp32->bf16 of all six weight matrices.
// ---------------------------------------------------------------------------
__global__ __launch_bounds__(256) void prep_k(
    const float* __restrict__ fc1_w, const float* __restrict__ mlp_in_w,
    const float* __restrict__ off_fc1_w, const float* __restrict__ fc2_w,
    const float* __restrict__ mlp_out_w, const float* __restrict__ off_fc2_w,
    unsigned short* __restrict__ wa, unsigned short* __restrict__ wc) {
  __shared__ float t[32][33];
  const int b = blockIdx.x;              // 0..863
  const int job = b / 144, tt = b - job * 144;
  const float* in = job == 0 ? fc1_w : job == 1 ? mlp_in_w : job == 2 ? off_fc1_w
                  : job == 3 ? fc2_w : job == 4 ? mlp_out_w : off_fc2_w;
  const int Cc = job < 3 ? 192 : 768;
  const int tc = Cc >> 5;
  const int tr0 = (tt / tc) << 5, tc0 = (tt - (tt / tc) * tc) << 5;
  const int lr = threadIdx.x >> 5, lc = threadIdx.x & 31;
#pragma unroll
  for (int p = 0; p < 4; p++)
    t[p * 8 + lr][lc] = in[(tr0 + p * 8 + lr) * Cc + tc0 + lc];
  __syncthreads();
#pragma unroll
  for (int p = 0; p < 4; p++) {
    const int orow = tc0 + p * 8 + lr;
    const int ocol = tr0 + lc;
    const unsigned short v = f2bf(t[lc][p * 8 + lr]);
    if (job < 3) wa[(job * 192 + orow) * 768 + ocol] = v;
    else         wc[orow * 576 + (job - 3) * 192 + ocol] = v;
  }
}

// ---------------------------------------------------------------------------
// gemm_a: Y = x(50432x768 fp32) @ wa-panel^T. BM=128, BN=192 (bx = path),
// BK=64, 256 threads = 4 waves (2m x 2n), per-wave 64x96 (48 MFMA/K-step).
// A: reg-staged fp32->bf16 into swizzled LDS; B: gl16 with pre-swizzled
// global source + linear LDS dest. 12 barriers per block.
// ---------------------------------------------------------------------------
__global__ __launch_bounds__(256, 1) void gemm_a_k(
    const float* __restrict__ x, const unsigned short* __restrict__ wa,
    const float* __restrict__ fc1_b, const float* __restrict__ mlp_in_b,
    unsigned short* __restrict__ h1, unsigned short* __restrict__ hcat,
    unsigned short* __restrict__ yoff) {
  __shared__ unsigned short As[2][128 * 64];   // 2 x 16 KB
  __shared__ unsigned short Bs[2][192 * 64];   // 2 x 24 KB
  const int tid = threadIdx.x, lane = tid & 63, w = tid >> 6;
  const int lid = swz(blockIdx.x, 3 * 394);
  const int by = lid / 3, bx = lid - by * 3;
  const int m0 = by * 128, n0 = bx * 192;

  // A staging: thread -> row t>>1, half (t&1)*32 fp32 cols
  const int arow = tid >> 1, ahalf = tid & 1;
  const float* ga = x + (size_t)(m0 + arow) * C_DIM + ahalf * 32;
  // B staging: per-lane pre-swizzled global source; linear LDS dest
  const int lrow8 = lane >> 3;                        // row&7
  const int csw = (((lane & 7) ^ lrow8) << 4);        // swizzled byte-in-row
  const char* gbB = (const char*)wa +
      (size_t)2 * (n0 + w * 48 + lrow8) * C_DIM + csw;

  float4 av[8];
  auto ldA = [&](int kt) {
    const float* p = ga + kt * 64;
#pragma unroll
    for (int j = 0; j < 8; j++) av[j] = *(const float4*)(p + j * 4);
  };
  auto wrA = [&](int b) {
#pragma unroll
    for (int jj = 0; jj < 4; jj++) {
      s16x8 v;
      const float4 u0 = av[2 * jj], u1 = av[2 * jj + 1];
      v[0] = (short)f2bf(u0.x); v[1] = (short)f2bf(u0.y);
      v[2] = (short)f2bf(u0.z); v[3] = (short)f2bf(u0.w);
      v[4] = (short)f2bf(u1.x); v[5] = (short)f2bf(u1.y);
      v[6] = (short)f2bf(u1.z); v[7] = (short)f2bf(u1.w);
      *(s16x8*)&As[b][lidx(arow, ahalf * 64 + jj * 16)] = v;
    }
  };
  auto stB = [&](int kt, int b) {
    char* lb = (char*)&Bs[b][0] + w * 6144 + lane * 16;
    const char* gb = gbB + kt * 128;
#pragma unroll
    for (int j = 0; j < 6; j++)
      gl16(gb + j * (8 * C_DIM * 2), lb + j * 1024);
  };

  f32x4 acc[4][6];
#pragma unroll
  for (int i = 0; i < 4; i++)
#pragma unroll
    for (int j = 0; j < 6; j++) acc[i][j] = (f32x4){0.f, 0.f, 0.f, 0.f};

  const int fr = lane & 15, fq = lane >> 4;
  const int wm = (w >> 1) * 64, wn = (w & 1) * 96;

  ldA(0); wrA(0); stB(0, 0); ldA(1);
  __syncthreads();
  for (int kt = 0; kt < 12; ++kt) {
    const int b = kt & 1;
    if (kt + 1 < 12) {
      stB(kt + 1, b ^ 1);
      wrA(b ^ 1);
      if (kt + 2 < 12) ldA(kt + 2);
    }
#pragma unroll
    for (int kk = 0; kk < 2; ++kk) {
      s16x8 af[4], bfv[6];
#pragma unroll
      for (int mi = 0; mi < 4; mi++)
        af[mi] = *(const s16x8*)&As[b][lidx(wm + mi * 16 + fr, kk * 64 + fq * 16)];
#pragma unroll
      for (int ni = 0; ni < 6; ni++)
        bfv[ni] = *(const s16x8*)&Bs[b][lidx(wn + ni * 16 + fr, kk * 64 + fq * 16)];
#pragma unroll
      for (int mi = 0; mi < 4; mi++)
#pragma unroll
        for (int ni = 0; ni < 6; ni++) mfma16(acc[mi][ni], af[mi], bfv[ni]);
    }
    __syncthreads();
  }

  unsigned short* dst; int stride;
  if (bx == 0)      { dst = h1;            stride = CA_DIM; }
  else if (bx == 1) { dst = hcat + CA_DIM; stride = 576; }
  else              { dst = yoff;          stride = CA_DIM; }
#pragma unroll
  for (int ni = 0; ni < 6; ni++) {
    const int ca = wn + ni * 16 + fr;
    const float bv = bx == 0 ? fc1_b[ca] : (bx == 1 ? mlp_in_b[ca] : 0.f);
#pragma unroll
    for (int mi = 0; mi < 4; mi++)
#pragma unroll
      for (int r = 0; r < 4; r++) {
        const int m = m0 + wm + mi * 16 + fq * 4 + r;
        float v = acc[mi][ni][r] + bv;
        if (bx == 1) v = v / (1.f + __expf(-1.702f * v));   // quick_gelu
        dst[(size_t)m * stride + ca] = f2bf(v);
      }
  }
}

// ---------------------------------------------------------------------------
// conv1d: 8 items/thread, channel chunk invariant -> weights in registers.
// ---------------------------------------------------------------------------
__global__ __launch_bounds__(256) void conv1d_k(
    const unsigned short* __restrict__ h1, const float* __restrict__ cw,
    const float* __restrict__ cb, unsigned short* __restrict__ hcat) {
  const int t0 = blockIdx.x * 256 + threadIdx.x;   // 591*256 = 151,296 threads
  const int c8 = t0 % 24;                          // stride 151296 % 24 == 0
  const int ca0 = c8 * 8;
  float w0[8], w1[8], w2[8], bb[8];
#pragma unroll
  for (int e = 0; e < 8; e++) {
    w0[e] = cw[(ca0 + e) * 3 + 0];
    w1[e] = cw[(ca0 + e) * 3 + 1];
    w2[e] = cw[(ca0 + e) * 3 + 2];
    bb[e] = cb[ca0 + e];
  }
  int m = t0 / 24;
#pragma unroll
  for (int k = 0; k < 8; k++, m += 6304) {
    const int t = m & 15;
    const int base = m * CA_DIM + ca0;
    uint4 z; z.x = z.y = z.z = z.w = 0u;
    const uint4 cu = *(const uint4*)(h1 + base);
    const uint4 pu = (t > 0) ? *(const uint4*)(h1 + base - CA_DIM) : z;
    const uint4 nu = (t < 15) ? *(const uint4*)(h1 + base + CA_DIM) : z;
    float pf[8], cf[8], nf[8];
    unp8(pu, pf); unp8(cu, cf); unp8(nu, nf);
    unsigned o[4];
#pragma unroll
    for (int e = 0; e < 8; e += 2) {
      const float r0 = w0[e] * pf[e] + w1[e] * cf[e] + w2[e] * nf[e] + bb[e];
      const float r1 = w0[e+1] * pf[e+1] + w1[e+1] * cf[e+1] + w2[e+1] * nf[e+1] + bb[e+1];
      o[e / 2] = (unsigned)f2bf(r0) | ((unsigned)f2bf(r1) << 16);
    }
    uint4 ov; ov.x = o[0]; ov.y = o[1]; ov.z = o[2]; ov.w = o[3];
    *(uint4*)(hcat + (size_t)m * 576 + ca0) = ov;
  }
}

// ---------------------------------------------------------------------------
// conv3d: one block per (frame n, channel quarter q). Stage
// d = (t>0 ? y[n]-y[n-1] : 0) + b1 as fp32 in LDS; 3x3 taps read from LDS.
// ---------------------------------------------------------------------------
__global__ __launch_bounds__(256) void conv3d_k(
    const unsigned short* __restrict__ y, const float* __restrict__ b1,
    const float* __restrict__ w3, const float* __restrict__ b2,
    unsigned short* __restrict__ hcat) {
  __shared__ float ds[196 * 48];
  __shared__ float w3s[9 * 48];
  __shared__ float b2s[48];
  const int blk = blockIdx.x;           // 1024 = 256 frames x 4 quarters
  const int n = blk >> 2, q = blk & 3;
  const int t = n & 15;
  const int ch0 = q * 48;
  const int tid = threadIdx.x;

  for (int j = tid; j < 432; j += 256) {
    const int c = j / 9, tap = j % 9;
    w3s[tap * 48 + c] = w3[(ch0 + c) * 9 + tap];
  }
  if (tid < 48) b2s[tid] = b2[ch0 + tid];

  for (int j = tid; j < 196 * 6; j += 256) {
    const int hw = j / 6, ck = j % 6;
    const int ca = ch0 + ck * 8;
    float dv[8];
    if (t > 0) {
      const unsigned short* p = y + ((size_t)(1 + hw) * 256 + n) * 192 + ca;
      float a0[8], a1[8];
      unp8(*(const uint4*)p, a0);
      unp8(*(const uint4*)(p - 192), a1);
#pragma unroll
      for (int e = 0; e < 8; e++) dv[e] = a0[e] - a1[e] + b1[ca + e];
    } else {
#pragma unroll
      for (int e = 0; e < 8; e++) dv[e] = b1[ca + e];
    }
#pragma unroll
    for (int e = 0; e < 8; e++) ds[hw * 48 + ck * 8 + e] = dv[e];
  }
  __syncthreads();

  for (int j = tid; j < 196 * 6; j += 256) {
    const int hw = j / 6, ck = j % 6;
    const int i = hw / 14, j0 = hw - i * 14;
    float acc[8];
#pragma unroll
    for (int e = 0; e < 8; e++) acc[e] = b2s[ck * 8 + e];
#pragma unroll
    for (int di = 0; di < 3; di++) {
      const int ii = i + di - 1;
      if (ii < 0 || ii >= 14) continue;
#pragma unroll
      for (int dj = 0; dj < 3; dj++) {
        const int jc = j0 + dj - 1;
        if (jc < 0 || jc >= 14) continue;
        const float* dp = &ds[(ii * 14 + jc) * 48 + ck * 8];
        const float* wp = &w3s[(di * 3 + dj) * 48 + ck * 8];
#pragma unroll
        for (int e = 0; e < 8; e++) acc[e] += wp[e] * dp[e];
      }
    }
    unsigned o[4];
#pragma unroll
    for (int e = 0; e < 8; e += 2)
      o[e / 2] = (unsigned)f2bf(acc[e]) | ((unsigned)f2bf(acc[e + 1]) << 16);
    uint4 ov; ov.x = o[0]; ov.y = o[1]; ov.z = o[2]; ov.w = o[3];
    *(uint4*)(hcat + ((size_t)(1 + hw) * 256 + n) * 576 + 384 + ch0 + ck * 8) = ov;
  }
}

// zero-fill hcat rows l=0 (m<256), cols [384,576)
__global__ __launch_bounds__(256) void zfill_k(unsigned short* __restrict__ hcat) {
  const int idx = blockIdx.x * 256 + threadIdx.x;   // 256*24
  const int m = idx / 24, ch = idx - (idx / 24) * 24;
  s16x8 z = (s16x8){0, 0, 0, 0, 0, 0, 0, 0};
  *(s16x8*)&hcat[m * 576 + 384 + ch * 8] = z;
}

// ---------------------------------------------------------------------------
// gemm_c: out = hcat(50432x576) @ wc^T + biases. BM=128, BN=128, BK=64,
// 256 threads = 4 waves (2x2), per-wave 64x64. Both operands via gl16 with
// pre-swizzled global source; 9 barriers per block.
// ---------------------------------------------------------------------------
__global__ __launch_bounds__(256, 1) void gemm_c_k(
    const unsigned short* __restrict__ hcat, const unsigned short* __restrict__ wc,
    const float* __restrict__ fc2_b, const float* __restrict__ mlp_out_b,
    const float* __restrict__ off_fc2_b, float* __restrict__ out) {
  __shared__ unsigned short As[2][128 * 64];   // 2 x 16 KB
  __shared__ unsigned short Bs[2][128 * 64];   // 2 x 16 KB
  const int tid = threadIdx.x, lane = tid & 63, w = tid >> 6;
  const int lid = swz(blockIdx.x, 6 * 394);
  const int by = lid / 6, bx = lid - by * 6;
  const int m0 = by * 128, n0 = bx * 128;

  const int lrow8 = lane >> 3;
  const int csw = (((lane & 7) ^ lrow8) << 4);
  const char* gAb = (const char*)hcat + (size_t)2 * (m0 + w * 32 + lrow8) * 576 + csw;
  const char* gBb = (const char*)wc   + (size_t)2 * (n0 + w * 32 + lrow8) * 576 + csw;

  auto stage = [&](int kt, int b) {
    char* la = (char*)&As[b][0] + w * 4096 + lane * 16;
    char* lb = (char*)&Bs[b][0] + w * 4096 + lane * 16;
    const char* ga = gAb + kt * 128;
    const char* gb = gBb + kt * 128;
#pragma unroll
    for (int j = 0; j < 4; j++) {
      gl16(ga + j * (8 * 576 * 2), la + j * 1024);
      gl16(gb + j * (8 * 576 * 2), lb + j * 1024);
    }
  };

  f32x4 acc[4][4];
#pragma unroll
  for (int i = 0; i < 4; i++)
#pragma unroll
    for (int j = 0; j < 4; j++) acc[i][j] = (f32x4){0.f, 0.f, 0.f, 0.f};

  const int fr = lane & 15, fq = lane >> 4;
  const int wm = (w >> 1) * 64, wn = (w & 1) * 64;

  stage(0, 0);
  __syncthreads();
  for (int kt = 0; kt < 9; ++kt) {
    const int b = kt & 1;
    if (kt + 1 < 9) stage(kt + 1, b ^ 1);
#pragma unroll
    for (int kk = 0; kk < 2; ++kk) {
      s16x8 af[4], bfv[4];
#pragma unroll
      for (int mi = 0; mi < 4; mi++)
        af[mi] = *(const s16x8*)&As[b][lidx(wm + mi * 16 + fr, kk * 64 + fq * 16)];
#pragma unroll
      for (int ni = 0; ni < 4; ni++)
        bfv[ni] = *(const s16x8*)&Bs[b][lidx(wn + ni * 16 + fr, kk * 64 + fq * 16)];
#pragma unroll
      for (int mi = 0; mi < 4; mi++)
#pragma unroll
        for (int ni = 0; ni < 4; ni++) mfma16(acc[mi][ni], af[mi], bfv[ni]);
    }
    __syncthreads();
  }

  float bv[4];
#pragma unroll
  for (int ni = 0; ni < 4; ni++) {
    const int c = n0 + wn + ni * 16 + fr;
    bv[ni] = fc2_b[c] + mlp_out_b[c] + (by >= 2 ? off_fc2_b[c] : 0.f);
  }
#pragma unroll
  for (int mi = 0; mi < 4; mi++)
#pragma unroll
    for (int r = 0; r < 4; r++) {
      const int m = m0 + wm + mi * 16 + fq * 4 + r;
      float* op = out + (size_t)m * C_DIM + n0 + wn;
#pragma unroll
      for (int ni = 0; ni < 4; ni++) op[ni * 16 + fr] = acc[mi][ni][r] + bv[ni];
    }
}

// ---------------------------------------------------------------------------
extern "C" void kernel_launch(void* const* d_in, const int* in_sizes, int n_in,
                              void* d_out, int out_size, void* d_ws, size_t ws_size,
                              hipStream_t stream) {
  const float* x          = (const float*)d_in[0];
  const float* fc1_w      = (const float*)d_in[2];
  const float* fc1_b      = (const float*)d_in[3];
  const float* conv_w     = (const float*)d_in[4];
  const float* conv_b     = (const float*)d_in[5];
  const float* fc2_w      = (const float*)d_in[6];
  const float* fc2_b      = (const float*)d_in[7];
  const float* off_fc1_w  = (const float*)d_in[8];
  const float* off_fc1_b  = (const float*)d_in[9];
  const float* off_conv_w = (const float*)d_in[10];
  const float* off_conv_b = (const float*)d_in[11];
  const float* off_fc2_w  = (const float*)d_in[12];
  const float* off_fc2_b  = (const float*)d_in[13];
  const float* mlp_in_w   = (const float*)d_in[14];
  const float* mlp_in_b   = (const float*)d_in[15];
  const float* mlp_out_w  = (const float*)d_in[16];
  const float* mlp_out_b  = (const float*)d_in[17];
  float* out = (float*)d_out;

  char* ws = (char*)d_ws;
  const size_t IB = (size_t)M_DIM * CA_DIM * 2;       // 19.4 MB
  unsigned short* h1   = (unsigned short*)(ws);
  unsigned short* yoff = (unsigned short*)(ws + IB);
  unsigned short* hcat = (unsigned short*)(ws + 2 * IB);          // [M][576]
  unsigned short* wa   = (unsigned short*)(ws + 2 * IB + (size_t)M_DIM * 576 * 2);
  unsigned short* wc   = wa + (size_t)576 * 768;

  prep_k<<<864, 256, 0, stream>>>(fc1_w, mlp_in_w, off_fc1_w, fc2_w, mlp_out_w,
                                  off_fc2_w, wa, wc);
  gemm_a_k<<<1182, 256, 0, stream>>>(x, wa, fc1_b, mlp_in_b, h1, hcat, yoff);
  conv1d_k<<<591, 256, 0, stream>>>(h1, conv_w, conv_b, hcat);
  conv3d_k<<<1024, 256, 0, stream>>>(yoff, off_fc1_b, off_conv_w, off_conv_b, hcat);
  zfill_k<<<24, 256, 0, stream>>>(hcat);
  gemm_c_k<<<2364, 256, 0, stream>>>(hcat, wc, fc2_b, mlp_out_b, off_fc2_b, out);
}

// Round 6
// 231.615 us; speedup vs baseline: 1.0627x; 1.0627x over previous
//
#include <hip/hip_runtime.h>

// ---- problem constants ----
#define L_DIM 197
#define N_DIM 256
#define C_DIM 768
#define CA_DIM 192
#define M_DIM (L_DIM * N_DIM)   // 50432

typedef short s16x8 __attribute__((ext_vector_type(8)));
typedef float f32x4 __attribute__((ext_vector_type(4)));

__device__ __forceinline__ unsigned short f2bf(float f) {
  unsigned x = __builtin_bit_cast(unsigned, f);
  x = (x + 0x7fffu + ((x >> 16) & 1u)) >> 16;   // RNE
  return (unsigned short)x;
}
__device__ __forceinline__ float bflo(unsigned u) { return __builtin_bit_cast(float, u << 16); }
__device__ __forceinline__ float bfhi(unsigned u) { return __builtin_bit_cast(float, u & 0xffff0000u); }

__device__ __forceinline__ void unp8(uint4 v, float* f) {
  f[0] = bflo(v.x); f[1] = bfhi(v.x); f[2] = bflo(v.y); f[3] = bfhi(v.y);
  f[4] = bflo(v.z); f[5] = bfhi(v.z); f[6] = bflo(v.w); f[7] = bfhi(v.w);
}

__device__ __forceinline__ void mfma16(f32x4& acc, s16x8 a, s16x8 b) {
  asm("v_mfma_f32_16x16x32_bf16 %0, %1, %2, %0" : "+v"(acc) : "v"(a), "v"(b));
}

// async global->LDS 16B
typedef const void __attribute__((address_space(1)))* gp_t;
typedef void __attribute__((address_space(3)))* lp_t;
__device__ __forceinline__ void gl16(const void* g, void* l) {
  __builtin_amdgcn_global_load_lds((gp_t)g, (lp_t)l, 16, 0, 0);
}

// bijective XCD-chunk swizzle (m204)
__device__ __forceinline__ int swz(int pid, int nwg) {
  const int q = nwg >> 3, r = nwg & 7, x = pid & 7, s = pid >> 3;
  return (x < r ? x * (q + 1) : r * (q + 1) + (x - r) * q) + s;
}

// ---------------------------------------------------------------------------
// prep: LDS-tiled transpose + fp32->bf16 of all six weight matrices.
// ---------------------------------------------------------------------------
__global__ __launch_bounds__(256) void prep_k(
    const float* __restrict__ fc1_w, const float* __restrict__ mlp_in_w,
    const float* __restrict__ off_fc1_w, const float* __restrict__ fc2_w,
    const float* __restrict__ mlp_out_w, const float* __restrict__ off_fc2_w,
    unsigned short* __restrict__ wa, unsigned short* __restrict__ wc) {
  __shared__ float t[32][33];
  const int b = blockIdx.x;              // 0..863
  const int job = b / 144, tt = b - job * 144;
  const float* in = job == 0 ? fc1_w : job == 1 ? mlp_in_w : job == 2 ? off_fc1_w
                  : job == 3 ? fc2_w : job == 4 ? mlp_out_w : off_fc2_w;
  const int Cc = job < 3 ? 192 : 768;
  const int tc = Cc >> 5;
  const int tr0 = (tt / tc) << 5, tc0 = (tt - (tt / tc) * tc) << 5;
  const int lr = threadIdx.x >> 5, lc = threadIdx.x & 31;
#pragma unroll
  for (int p = 0; p < 4; p++)
    t[p * 8 + lr][lc] = in[(tr0 + p * 8 + lr) * Cc + tc0 + lc];
  __syncthreads();
#pragma unroll
  for (int p = 0; p < 4; p++) {
    const int orow = tc0 + p * 8 + lr;
    const int ocol = tr0 + lc;
    const unsigned short v = f2bf(t[lc][p * 8 + lr]);
    if (job < 3) wa[(job * 192 + orow) * 768 + ocol] = v;
    else         wc[orow * 576 + (job - 3) * 192 + ocol] = v;
  }
}

// ---------------------------------------------------------------------------
// gemm_a: Y = x(50432x768 fp32) @ wa-panel^T. BM=128, BN=192 (bx = path),
// BK=32, 512 threads = 8 waves (2m x 4n), per-wave 64x48 -> acc[4][3]
// (48 AGPR; small acc => 4 waves/SIMD => 2 blocks/CU, 50% occupancy).
// A: reg-staged fp32->bf16; B: global_load_lds. Linear LDS (no swizzle:
// conflicts are invisible in the 2-phase latency regime).
// ---------------------------------------------------------------------------
__global__ __launch_bounds__(512, 4) void gemm_a_k(
    const float* __restrict__ x, const unsigned short* __restrict__ wa,
    const float* __restrict__ fc1_b, const float* __restrict__ mlp_in_b,
    unsigned short* __restrict__ h1, unsigned short* __restrict__ hcat,
    unsigned short* __restrict__ yoff) {
  __shared__ unsigned short As[2][128 * 32];   // 2 x 8 KB
  __shared__ unsigned short Bs[2][192 * 32];   // 2 x 12 KB
  const int tid = threadIdx.x, lane = tid & 63, w = tid >> 6;
  const int lid = swz(blockIdx.x, 3 * 394);
  const int by = lid / 3, bx = lid - by * 3;
  const int m0 = by * 128, n0 = bx * 192;

  // A: thread -> row tid>>2 (0..127), 8 fp32 at col (tid&3)*8
  const int ar = tid >> 2, ac = (tid & 3) << 3;
  const float* ga = x + (size_t)(m0 + ar) * C_DIM + ac;
  // B: chunk tid (rows 0..127) + chunk 512+tid for tid<256 (rows 128..191)
  const unsigned short* gb0 = wa + (size_t)(n0 + ar) * C_DIM + ac;
  const unsigned short* gb1 = wa + (size_t)(n0 + 128 + ar) * C_DIM + ac;

  float4 av[2];
  auto ldA = [&](int kt) {
    const float* p = ga + kt * 32;
    av[0] = *(const float4*)p;
    av[1] = *(const float4*)(p + 4);
  };
  auto wrA = [&](int b) {
    s16x8 v;
    v[0] = (short)f2bf(av[0].x); v[1] = (short)f2bf(av[0].y);
    v[2] = (short)f2bf(av[0].z); v[3] = (short)f2bf(av[0].w);
    v[4] = (short)f2bf(av[1].x); v[5] = (short)f2bf(av[1].y);
    v[6] = (short)f2bf(av[1].z); v[7] = (short)f2bf(av[1].w);
    *(s16x8*)&As[b][ar * 32 + ac] = v;
  };
  auto stB = [&](int kt, int b) {
    gl16(gb0 + kt * 32, &Bs[b][ar * 32 + ac]);
    if (tid < 256) gl16(gb1 + kt * 32, &Bs[b][(128 + ar) * 32 + ac]);
  };

  f32x4 acc[4][3];
#pragma unroll
  for (int i = 0; i < 4; i++)
#pragma unroll
    for (int j = 0; j < 3; j++) acc[i][j] = (f32x4){0.f, 0.f, 0.f, 0.f};

  const int fr = lane & 15, fq = lane >> 4;
  const int wm = (w >> 2) * 64, wn = (w & 3) * 48;

  ldA(0); wrA(0); stB(0, 0); ldA(1);
  __syncthreads();
  for (int kt = 0; kt < 24; ++kt) {
    const int b = kt & 1;
    if (kt + 1 < 24) {
      stB(kt + 1, b ^ 1);
      wrA(b ^ 1);
      if (kt + 2 < 24) ldA(kt + 2);
    }
    s16x8 af[4], bfv[3];
#pragma unroll
    for (int mi = 0; mi < 4; mi++)
      af[mi] = *(const s16x8*)&As[b][(wm + mi * 16 + fr) * 32 + fq * 8];
#pragma unroll
    for (int ni = 0; ni < 3; ni++)
      bfv[ni] = *(const s16x8*)&Bs[b][(wn + ni * 16 + fr) * 32 + fq * 8];
#pragma unroll
    for (int mi = 0; mi < 4; mi++)
#pragma unroll
      for (int ni = 0; ni < 3; ni++) mfma16(acc[mi][ni], af[mi], bfv[ni]);
    __syncthreads();
  }

  unsigned short* dst; int stride;
  if (bx == 0)      { dst = h1;            stride = CA_DIM; }
  else if (bx == 1) { dst = hcat + CA_DIM; stride = 576; }
  else              { dst = yoff;          stride = CA_DIM; }
#pragma unroll
  for (int ni = 0; ni < 3; ni++) {
    const int ca = wn + ni * 16 + fr;
    const float bv = bx == 0 ? fc1_b[ca] : (bx == 1 ? mlp_in_b[ca] : 0.f);
#pragma unroll
    for (int mi = 0; mi < 4; mi++)
#pragma unroll
      for (int r = 0; r < 4; r++) {
        const int m = m0 + wm + mi * 16 + fq * 4 + r;
        float v = acc[mi][ni][r] + bv;
        if (bx == 1) v = v / (1.f + __expf(-1.702f * v));   // quick_gelu
        dst[(size_t)m * stride + ca] = f2bf(v);
      }
  }
}

// ---------------------------------------------------------------------------
// conv1d: 8 items/thread, channel chunk invariant -> weights in registers.
// ---------------------------------------------------------------------------
__global__ __launch_bounds__(256) void conv1d_k(
    const unsigned short* __restrict__ h1, const float* __restrict__ cw,
    const float* __restrict__ cb, unsigned short* __restrict__ hcat) {
  const int t0 = blockIdx.x * 256 + threadIdx.x;   // 591*256 = 151,296 threads
  const int c8 = t0 % 24;                          // stride 151296 % 24 == 0
  const int ca0 = c8 * 8;
  float w0[8], w1[8], w2[8], bb[8];
#pragma unroll
  for (int e = 0; e < 8; e++) {
    w0[e] = cw[(ca0 + e) * 3 + 0];
    w1[e] = cw[(ca0 + e) * 3 + 1];
    w2[e] = cw[(ca0 + e) * 3 + 2];
    bb[e] = cb[ca0 + e];
  }
  int m = t0 / 24;
#pragma unroll
  for (int k = 0; k < 8; k++, m += 6304) {
    const int t = m & 15;
    const int base = m * CA_DIM + ca0;
    uint4 z; z.x = z.y = z.z = z.w = 0u;
    const uint4 cu = *(const uint4*)(h1 + base);
    const uint4 pu = (t > 0) ? *(const uint4*)(h1 + base - CA_DIM) : z;
    const uint4 nu = (t < 15) ? *(const uint4*)(h1 + base + CA_DIM) : z;
    float pf[8], cf[8], nf[8];
    unp8(pu, pf); unp8(cu, cf); unp8(nu, nf);
    unsigned o[4];
#pragma unroll
    for (int e = 0; e < 8; e += 2) {
      const float r0 = w0[e] * pf[e] + w1[e] * cf[e] + w2[e] * nf[e] + bb[e];
      const float r1 = w0[e+1] * pf[e+1] + w1[e+1] * cf[e+1] + w2[e+1] * nf[e+1] + bb[e+1];
      o[e / 2] = (unsigned)f2bf(r0) | ((unsigned)f2bf(r1) << 16);
    }
    uint4 ov; ov.x = o[0]; ov.y = o[1]; ov.z = o[2]; ov.w = o[3];
    *(uint4*)(hcat + (size_t)m * 576 + ca0) = ov;
  }
}

// ---------------------------------------------------------------------------
// conv3d: one block per (frame n, channel quarter q). Stage
// d = (t>0 ? y[n]-y[n-1] : 0) + b1 as fp32 in LDS; 3x3 taps read from LDS.
// ---------------------------------------------------------------------------
__global__ __launch_bounds__(256) void conv3d_k(
    const unsigned short* __restrict__ y, const float* __restrict__ b1,
    const float* __restrict__ w3, const float* __restrict__ b2,
    unsigned short* __restrict__ hcat) {
  __shared__ float ds[196 * 48];
  __shared__ float w3s[9 * 48];
  __shared__ float b2s[48];
  const int blk = blockIdx.x;           // 1024 = 256 frames x 4 quarters
  const int n = blk >> 2, q = blk & 3;
  const int t = n & 15;
  const int ch0 = q * 48;
  const int tid = threadIdx.x;

  for (int j = tid; j < 432; j += 256) {
    const int c = j / 9, tap = j % 9;
    w3s[tap * 48 + c] = w3[(ch0 + c) * 9 + tap];
  }
  if (tid < 48) b2s[tid] = b2[ch0 + tid];

  for (int j = tid; j < 196 * 6; j += 256) {
    const int hw = j / 6, ck = j % 6;
    const int ca = ch0 + ck * 8;
    float dv[8];
    if (t > 0) {
      const unsigned short* p = y + ((size_t)(1 + hw) * 256 + n) * 192 + ca;
      float a0[8], a1[8];
      unp8(*(const uint4*)p, a0);
      unp8(*(const uint4*)(p - 192), a1);
#pragma unroll
      for (int e = 0; e < 8; e++) dv[e] = a0[e] - a1[e] + b1[ca + e];
    } else {
#pragma unroll
      for (int e = 0; e < 8; e++) dv[e] = b1[ca + e];
    }
#pragma unroll
    for (int e = 0; e < 8; e++) ds[hw * 48 + ck * 8 + e] = dv[e];
  }
  __syncthreads();

  for (int j = tid; j < 196 * 6; j += 256) {
    const int hw = j / 6, ck = j % 6;
    const int i = hw / 14, j0 = hw - i * 14;
    float acc[8];
#pragma unroll
    for (int e = 0; e < 8; e++) acc[e] = b2s[ck * 8 + e];
#pragma unroll
    for (int di = 0; di < 3; di++) {
      const int ii = i + di - 1;
      if (ii < 0 || ii >= 14) continue;
#pragma unroll
      for (int dj = 0; dj < 3; dj++) {
        const int jc = j0 + dj - 1;
        if (jc < 0 || jc >= 14) continue;
        const float* dp = &ds[(ii * 14 + jc) * 48 + ck * 8];
        const float* wp = &w3s[(di * 3 + dj) * 48 + ck * 8];
#pragma unroll
        for (int e = 0; e < 8; e++) acc[e] += wp[e] * dp[e];
      }
    }
    unsigned o[4];
#pragma unroll
    for (int e = 0; e < 8; e += 2)
      o[e / 2] = (unsigned)f2bf(acc[e]) | ((unsigned)f2bf(acc[e + 1]) << 16);
    uint4 ov; ov.x = o[0]; ov.y = o[1]; ov.z = o[2]; ov.w = o[3];
    *(uint4*)(hcat + ((size_t)(1 + hw) * 256 + n) * 576 + 384 + ch0 + ck * 8) = ov;
  }
}

// zero-fill hcat rows l=0 (m<256), cols [384,576)
__global__ __launch_bounds__(256) void zfill_k(unsigned short* __restrict__ hcat) {
  const int idx = blockIdx.x * 256 + threadIdx.x;   // 256*24
  const int m = idx / 24, ch = idx - (idx / 24) * 24;
  s16x8 z = (s16x8){0, 0, 0, 0, 0, 0, 0, 0};
  *(s16x8*)&hcat[m * 576 + 384 + ch * 8] = z;
}

// ---------------------------------------------------------------------------
// gemm_c: out = hcat(50432x576) @ wc^T + biases. BM=128, BN=128, BK=32,
// 512 threads = 8 waves (2m x 4n), per-wave 64x32 -> acc[4][2] (32 AGPR).
// Both operands via global_load_lds; linear LDS.
// ---------------------------------------------------------------------------
__global__ __launch_bounds__(512, 4) void gemm_c_k(
    const unsigned short* __restrict__ hcat, const unsigned short* __restrict__ wc,
    const float* __restrict__ fc2_b, const float* __restrict__ mlp_out_b,
    const float* __restrict__ off_fc2_b, float* __restrict__ out) {
  __shared__ unsigned short As[2][128 * 32];   // 2 x 8 KB
  __shared__ unsigned short Bs[2][128 * 32];   // 2 x 8 KB
  const int tid = threadIdx.x, lane = tid & 63, w = tid >> 6;
  const int lid = swz(blockIdx.x, 6 * 394);
  const int by = lid / 6, bx = lid - by * 6;
  const int m0 = by * 128, n0 = bx * 128;

  const int sr = tid >> 2, sc = (tid & 3) << 3;   // row 0..127, col 0/8/16/24
  const unsigned short* gA = hcat + (size_t)(m0 + sr) * 576 + sc;
  const unsigned short* gB = wc + (size_t)(n0 + sr) * 576 + sc;
  auto stage = [&](int kt, int b) {
    gl16(gA + kt * 32, &As[b][sr * 32 + sc]);
    gl16(gB + kt * 32, &Bs[b][sr * 32 + sc]);
  };

  f32x4 acc[4][2];
#pragma unroll
  for (int i = 0; i < 4; i++)
#pragma unroll
    for (int j = 0; j < 2; j++) acc[i][j] = (f32x4){0.f, 0.f, 0.f, 0.f};

  const int fr = lane & 15, fq = lane >> 4;
  const int wm = (w >> 2) * 64, wn = (w & 3) * 32;

  stage(0, 0);
  __syncthreads();
  for (int kt = 0; kt < 18; ++kt) {
    const int b = kt & 1;
    if (kt + 1 < 18) stage(kt + 1, b ^ 1);
    s16x8 af[4], bfv[2];
#pragma unroll
    for (int mi = 0; mi < 4; mi++)
      af[mi] = *(const s16x8*)&As[b][(wm + mi * 16 + fr) * 32 + fq * 8];
#pragma unroll
    for (int ni = 0; ni < 2; ni++)
      bfv[ni] = *(const s16x8*)&Bs[b][(wn + ni * 16 + fr) * 32 + fq * 8];
#pragma unroll
    for (int mi = 0; mi < 4; mi++)
#pragma unroll
      for (int ni = 0; ni < 2; ni++) mfma16(acc[mi][ni], af[mi], bfv[ni]);
    __syncthreads();
  }

  float bv[2];
#pragma unroll
  for (int ni = 0; ni < 2; ni++) {
    const int c = n0 + wn + ni * 16 + fr;
    bv[ni] = fc2_b[c] + mlp_out_b[c] + (by >= 2 ? off_fc2_b[c] : 0.f);
  }
#pragma unroll
  for (int mi = 0; mi < 4; mi++)
#pragma unroll
    for (int r = 0; r < 4; r++) {
      const int m = m0 + wm + mi * 16 + fq * 4 + r;
      float* op = out + (size_t)m * C_DIM + n0 + wn;
#pragma unroll
      for (int ni = 0; ni < 2; ni++) op[ni * 16 + fr] = acc[mi][ni][r] + bv[ni];
    }
}

// ---------------------------------------------------------------------------
extern "C" void kernel_launch(void* const* d_in, const int* in_sizes, int n_in,
                              void* d_out, int out_size, void* d_ws, size_t ws_size,
                              hipStream_t stream) {
  const float* x          = (const float*)d_in[0];
  const float* fc1_w      = (const float*)d_in[2];
  const float* fc1_b      = (const float*)d_in[3];
  const float* conv_w     = (const float*)d_in[4];
  const float* conv_b     = (const float*)d_in[5];
  const float* fc2_w      = (const float*)d_in[6];
  const float* fc2_b      = (const float*)d_in[7];
  const float* off_fc1_w  = (const float*)d_in[8];
  const float* off_fc1_b  = (const float*)d_in[9];
  const float* off_conv_w = (const float*)d_in[10];
  const float* off_conv_b = (const float*)d_in[11];
  const float* off_fc2_w  = (const float*)d_in[12];
  const float* off_fc2_b  = (const float*)d_in[13];
  const float* mlp_in_w   = (const float*)d_in[14];
  const float* mlp_in_b   = (const float*)d_in[15];
  const float* mlp_out_w  = (const float*)d_in[16];
  const float* mlp_out_b  = (const float*)d_in[17];
  float* out = (float*)d_out;

  char* ws = (char*)d_ws;
  const size_t IB = (size_t)M_DIM * CA_DIM * 2;       // 19.4 MB
  unsigned short* h1   = (unsigned short*)(ws);
  unsigned short* yoff = (unsigned short*)(ws + IB);
  unsigned short* hcat = (unsigned short*)(ws + 2 * IB);          // [M][576]
  unsigned short* wa   = (unsigned short*)(ws + 2 * IB + (size_t)M_DIM * 576 * 2);
  unsigned short* wc   = wa + (size_t)576 * 768;

  prep_k<<<864, 256, 0, stream>>>(fc1_w, mlp_in_w, off_fc1_w, fc2_w, mlp_out_w,
                                  off_fc2_w, wa, wc);
  gemm_a_k<<<1182, 512, 0, stream>>>(x, wa, fc1_b, mlp_in_b, h1, hcat, yoff);
  conv1d_k<<<591, 256, 0, stream>>>(h1, conv_w, conv_b, hcat);
  conv3d_k<<<1024, 256, 0, stream>>>(yoff, off_fc1_b, off_conv_w, off_conv_b, hcat);
  zfill_k<<<24, 256, 0, stream>>>(hcat);
  gemm_c_k<<<2364, 512, 0, stream>>>(hcat, wc, fc2_b, mlp_out_b, off_fc2_b, out);
}

// Round 8
// 219.586 us; speedup vs baseline: 1.1209x; 1.0548x over previous
//
#include <hip/hip_runtime.h>

// ---- problem constants ----
#define L_DIM 197
#define N_DIM 256
#define C_DIM 768
#define CA_DIM 192
#define M_DIM (L_DIM * N_DIM)   // 50432

typedef short s16x8 __attribute__((ext_vector_type(8)));
typedef float f32x4 __attribute__((ext_vector_type(4)));

__device__ __forceinline__ unsigned short f2bf(float f) {
  unsigned x = __builtin_bit_cast(unsigned, f);
  x = (x + 0x7fffu + ((x >> 16) & 1u)) >> 16;   // RNE
  return (unsigned short)x;
}
__device__ __forceinline__ float bflo(unsigned u) { return __builtin_bit_cast(float, u << 16); }
__device__ __forceinline__ float bfhi(unsigned u) { return __builtin_bit_cast(float, u & 0xffff0000u); }

__device__ __forceinline__ void unp8(uint4 v, float* f) {
  f[0] = bflo(v.x); f[1] = bfhi(v.x); f[2] = bflo(v.y); f[3] = bfhi(v.y);
  f[4] = bflo(v.z); f[5] = bfhi(v.z); f[6] = bflo(v.w); f[7] = bfhi(v.w);
}

__device__ __forceinline__ void mfma16(f32x4& acc, s16x8 a, s16x8 b) {
  asm("v_mfma_f32_16x16x32_bf16 %0, %1, %2, %0" : "+v"(acc) : "v"(a), "v"(b));
}

// async global->LDS 16B.  HW writes wave-uniform base + lane*16 — every call
// below is arranged so the per-lane LDS byte address == base + 16*lane.
typedef const void __attribute__((address_space(1)))* gp_t;
typedef void __attribute__((address_space(3)))* lp_t;
__device__ __forceinline__ void gl16(const void* g, void* l) {
  __builtin_amdgcn_global_load_lds((gp_t)g, (lp_t)l, 16, 0, 0);
}

// bijective XCD-chunk swizzle (m204)
__device__ __forceinline__ int swz(int pid, int nwg) {
  const int q = nwg >> 3, r = nwg & 7, x = pid & 7, s = pid >> 3;
  return (x < r ? x * (q + 1) : r * (q + 1) + (x - r) * q) + s;
}

// ---------------------------------------------------------------------------
// prep: LDS-tiled transpose + fp32->bf16 of all six weight matrices.
// ---------------------------------------------------------------------------
__global__ __launch_bounds__(256) void prep_k(
    const float* __restrict__ fc1_w, const float* __restrict__ mlp_in_w,
    const float* __restrict__ off_fc1_w, const float* __restrict__ fc2_w,
    const float* __restrict__ mlp_out_w, const float* __restrict__ off_fc2_w,
    unsigned short* __restrict__ wa, unsigned short* __restrict__ wc) {
  __shared__ float t[32][33];
  const int b = blockIdx.x;              // 0..863
  const int job = b / 144, tt = b - job * 144;
  const float* in = job == 0 ? fc1_w : job == 1 ? mlp_in_w : job == 2 ? off_fc1_w
                  : job == 3 ? fc2_w : job == 4 ? mlp_out_w : off_fc2_w;
  const int Cc = job < 3 ? 192 : 768;
  const int tc = Cc >> 5;
  const int tr0 = (tt / tc) << 5, tc0 = (tt - (tt / tc) * tc) << 5;
  const int lr = threadIdx.x >> 5, lc = threadIdx.x & 31;
#pragma unroll
  for (int p = 0; p < 4; p++)
    t[p * 8 + lr][lc] = in[(tr0 + p * 8 + lr) * Cc + tc0 + lc];
  __syncthreads();
#pragma unroll
  for (int p = 0; p < 4; p++) {
    const int orow = tc0 + p * 8 + lr;
    const int ocol = tr0 + lc;
    const unsigned short v = f2bf(t[lc][p * 8 + lr]);
    if (job < 3) wa[(job * 192 + orow) * 768 + ocol] = v;
    else         wc[orow * 576 + (job - 3) * 192 + ocol] = v;
  }
}

// ---------------------------------------------------------------------------
// xcvt: x fp32 -> bf16, vectorized grid-stride.
// ---------------------------------------------------------------------------
__global__ __launch_bounds__(256) void xcvt_k(const float* __restrict__ x,
                                              unsigned short* __restrict__ xb) {
  const int total8 = M_DIM * C_DIM / 8;     // 4,841,472
  const int step = gridDim.x * 256;
  for (int i = blockIdx.x * 256 + threadIdx.x; i < total8; i += step) {
    const float4 a = *(const float4*)(x + (size_t)i * 8);
    const float4 b = *(const float4*)(x + (size_t)i * 8 + 4);
    s16x8 v;
    v[0] = (short)f2bf(a.x); v[1] = (short)f2bf(a.y);
    v[2] = (short)f2bf(a.z); v[3] = (short)f2bf(a.w);
    v[4] = (short)f2bf(b.x); v[5] = (short)f2bf(b.y);
    v[6] = (short)f2bf(b.z); v[7] = (short)f2bf(b.w);
    *(s16x8*)(xb + (size_t)i * 8) = v;
  }
}

// ---------------------------------------------------------------------------
// gemm_a: Y = xb(50432x768 bf16) @ wa-panel^T. BM=128, BN=192 (bx = path),
// BK=32, 256 threads = 4 waves (2m x 2n), per-wave 64x96 (24 MFMA/K-step).
// Both operands via global_load_lds; every call is 16B/lane-stride clean.
// Fused epilogues:
//   bx0: conv1d over t (t = fq*4+r is fragment-local; 2 shuffles) -> hcat[0:192)
//   bx1: quickGELU(+mlp_in_b)                                     -> hcat[192:384)
//   bx2: temporal diff + off_fc1_b                                -> hcat[384:576)
// ---------------------------------------------------------------------------
__global__ __launch_bounds__(256, 1) void gemm_a_k(
    const unsigned short* __restrict__ xb, const unsigned short* __restrict__ wa,
    const float* __restrict__ fc1_b, const float* __restrict__ mlp_in_b,
    const float* __restrict__ cw, const float* __restrict__ cb,
    const float* __restrict__ off_b1, unsigned short* __restrict__ hcat) {
  __shared__ unsigned short As[2][128 * 32];   // 2 x 8 KB
  __shared__ unsigned short Bs[2][192 * 32];   // 2 x 12 KB
  const int tid = threadIdx.x, lane = tid & 63, w = tid >> 6;
  const int lid = swz(blockIdx.x, 3 * 394);
  const int by = lid / 3, bx = lid - by * 3;
  const int m0 = by * 128, n0 = bx * 192;

  // staging: row sr = tid>>2, col sc = (tid&3)*8  ->  LDS byte = 16*tid
  const int sr = tid >> 2, sc = (tid & 3) * 8;
  const unsigned short* gA0 = xb + (size_t)(m0 + sr) * C_DIM + sc;        // rows 0-63
  const unsigned short* gA1 = xb + (size_t)(m0 + 64 + sr) * C_DIM + sc;   // rows 64-127
  const unsigned short* gB = wa + (size_t)(n0 + sr) * C_DIM + sc;

  auto stage = [&](int kt, int b) {
    gl16(gA0 + kt * 32, &As[b][sr * 32 + sc]);
    gl16(gA1 + kt * 32, &As[b][(64 + sr) * 32 + sc]);
    const unsigned short* pb = gB + kt * 32;
    gl16(pb,               &Bs[b][sr * 32 + sc]);
    gl16(pb + 64 * C_DIM,  &Bs[b][(64 + sr) * 32 + sc]);
    gl16(pb + 128 * C_DIM, &Bs[b][(128 + sr) * 32 + sc]);
  };

  f32x4 acc[4][6];
#pragma unroll
  for (int i = 0; i < 4; i++)
#pragma unroll
    for (int j = 0; j < 6; j++) acc[i][j] = (f32x4){0.f, 0.f, 0.f, 0.f};

  const int fr = lane & 15, fq = lane >> 4;
  const int wm = (w >> 1) * 64, wn = (w & 1) * 96;

  stage(0, 0);
  __syncthreads();
  for (int kt = 0; kt < 24; ++kt) {
    const int b = kt & 1;
    if (kt + 1 < 24) stage(kt + 1, b ^ 1);
    s16x8 af[4], bfv[6];
#pragma unroll
    for (int mi = 0; mi < 4; mi++)
      af[mi] = *(const s16x8*)&As[b][(wm + mi * 16 + fr) * 32 + fq * 8];
#pragma unroll
    for (int ni = 0; ni < 6; ni++)
      bfv[ni] = *(const s16x8*)&Bs[b][(wn + ni * 16 + fr) * 32 + fq * 8];
#pragma unroll
    for (int mi = 0; mi < 4; mi++)
#pragma unroll
      for (int ni = 0; ni < 6; ni++) mfma16(acc[mi][ni], af[mi], bfv[ni]);
    __syncthreads();
  }

  // ---- fused epilogues (t = fq*4 + r within each 16-row fragment) ----
  if (bx == 0) {
    // conv1d: out[t] = w0*h[t-1] + w1*h[t] + w2*h[t+1] + cb  (zero-padded)
#pragma unroll
    for (int ni = 0; ni < 6; ni++) {
      const int ca = wn + ni * 16 + fr;
      const float bv = fc1_b[ca];
      const float w0 = cw[ca * 3], w1 = cw[ca * 3 + 1], w2 = cw[ca * 3 + 2];
      const float cbv = cb[ca];
#pragma unroll
      for (int mi = 0; mi < 4; mi++) {
        const float v0 = acc[mi][ni][0] + bv, v1 = acc[mi][ni][1] + bv;
        const float v2 = acc[mi][ni][2] + bv, v3 = acc[mi][ni][3] + bv;
        const float pv3 = __shfl_up(v3, 16);    // h[t-1] when r==0 (from lane-16)
        const float nv0 = __shfl_down(v0, 16);  // h[t+1] when r==3 (from lane+16)
        const float p0 = fq > 0 ? pv3 : 0.f;
        const float n3 = fq < 3 ? nv0 : 0.f;
        const int mb = m0 + wm + mi * 16 + fq * 4;
        hcat[(size_t)(mb + 0) * 576 + ca] = f2bf(w0 * p0 + w1 * v0 + w2 * v1 + cbv);
        hcat[(size_t)(mb + 1) * 576 + ca] = f2bf(w0 * v0 + w1 * v1 + w2 * v2 + cbv);
        hcat[(size_t)(mb + 2) * 576 + ca] = f2bf(w0 * v1 + w1 * v2 + w2 * v3 + cbv);
        hcat[(size_t)(mb + 3) * 576 + ca] = f2bf(w0 * v2 + w1 * v3 + w2 * n3 + cbv);
      }
    }
  } else if (bx == 1) {
#pragma unroll
    for (int ni = 0; ni < 6; ni++) {
      const int ca = wn + ni * 16 + fr;
      const float bv = mlp_in_b[ca];
#pragma unroll
      for (int mi = 0; mi < 4; mi++)
#pragma unroll
        for (int r = 0; r < 4; r++) {
          const int m = m0 + wm + mi * 16 + fq * 4 + r;
          float v = acc[mi][ni][r] + bv;
          v = v / (1.f + __expf(-1.702f * v));   // quick_gelu
          hcat[(size_t)m * 576 + 192 + ca] = f2bf(v);
        }
    }
  } else {
    // temporal diff: d[t] = (t>0 ? y[t]-y[t-1] : 0) + off_fc1_b
#pragma unroll
    for (int ni = 0; ni < 6; ni++) {
      const int ca = wn + ni * 16 + fr;
      const float bv = off_b1[ca];
#pragma unroll
      for (int mi = 0; mi < 4; mi++) {
        const float v0 = acc[mi][ni][0], v1 = acc[mi][ni][1];
        const float v2 = acc[mi][ni][2], v3 = acc[mi][ni][3];
        const float pv3 = __shfl_up(v3, 16);
        const int mb = m0 + wm + mi * 16 + fq * 4;
        const float o0 = (fq == 0) ? bv : (v0 - pv3 + bv);   // t==0 iff fq==0 (r=0)
        hcat[(size_t)(mb + 0) * 576 + 384 + ca] = f2bf(o0);
        hcat[(size_t)(mb + 1) * 576 + 384 + ca] = f2bf(v1 - v0 + bv);
        hcat[(size_t)(mb + 2) * 576 + 384 + ca] = f2bf(v2 - v1 + bv);
        hcat[(size_t)(mb + 3) * 576 + 384 + ca] = f2bf(v3 - v2 + bv);
      }
    }
  }
}

// ---------------------------------------------------------------------------
// conv3d: spatial-only 3x3 depthwise, IN-PLACE on hcat cols [384,576) rows
// l>=1. Block-local: one block per (frame n, channel quarter q) stages all of
// its rows into LDS, barriers, writes back. Temporal diff already applied.
// ---------------------------------------------------------------------------
__global__ __launch_bounds__(256) void conv3d_k(
    const float* __restrict__ w3, const float* __restrict__ b2,
    unsigned short* __restrict__ hcat) {
  __shared__ float ds[196 * 48];
  __shared__ float w3s[9 * 48];
  __shared__ float b2s[48];
  const int blk = blockIdx.x;           // 1024 = 256 frames x 4 quarters
  const int n = blk >> 2, q = blk & 3;
  const int ch0 = q * 48;
  const int tid = threadIdx.x;

  for (int j = tid; j < 432; j += 256) {
    const int c = j / 9, tap = j % 9;
    w3s[tap * 48 + c] = w3[(ch0 + c) * 9 + tap];
  }
  if (tid < 48) b2s[tid] = b2[ch0 + tid];

  for (int j = tid; j < 196 * 6; j += 256) {
    const int hw = j / 6, ck = j % 6;
    float dv[8];
    unp8(*(const uint4*)(hcat + ((size_t)(1 + hw) * 256 + n) * 576 + 384 + ch0 + ck * 8), dv);
#pragma unroll
    for (int e = 0; e < 8; e++) ds[hw * 48 + ck * 8 + e] = dv[e];
  }
  __syncthreads();

  for (int j = tid; j < 196 * 6; j += 256) {
    const int hw = j / 6, ck = j % 6;
    const int i = hw / 14, j0 = hw - i * 14;
    float acc[8];
#pragma unroll
    for (int e = 0; e < 8; e++) acc[e] = b2s[ck * 8 + e];
#pragma unroll
    for (int di = 0; di < 3; di++) {
      const int ii = i + di - 1;
      if (ii < 0 || ii >= 14) continue;
#pragma unroll
      for (int dj = 0; dj < 3; dj++) {
        const int jc = j0 + dj - 1;
        if (jc < 0 || jc >= 14) continue;
        const float* dp = &ds[(ii * 14 + jc) * 48 + ck * 8];
        const float* wp = &w3s[(di * 3 + dj) * 48 + ck * 8];
#pragma unroll
        for (int e = 0; e < 8; e++) acc[e] += wp[e] * dp[e];
      }
    }
    unsigned o[4];
#pragma unroll
    for (int e = 0; e < 8; e += 2)
      o[e / 2] = (unsigned)f2bf(acc[e]) | ((unsigned)f2bf(acc[e + 1]) << 16);
    uint4 ov; ov.x = o[0]; ov.y = o[1]; ov.z = o[2]; ov.w = o[3];
    *(uint4*)(hcat + ((size_t)(1 + hw) * 256 + n) * 576 + 384 + ch0 + ck * 8) = ov;
  }
}

// zero-fill hcat rows l=0 (m<256), cols [384,576)
__global__ __launch_bounds__(256) void zfill_k(unsigned short* __restrict__ hcat) {
  const int idx = blockIdx.x * 256 + threadIdx.x;   // 256*24
  const int m = idx / 24, ch = idx - (idx / 24) * 24;
  s16x8 z = (s16x8){0, 0, 0, 0, 0, 0, 0, 0};
  *(s16x8*)&hcat[(size_t)m * 576 + 384 + ch * 8] = z;
}

// ---------------------------------------------------------------------------
// gemm_c: out = hcat(50432x576) @ wc^T + biases. BM=128, BN=128, BK=32,
// 256 threads = 4 waves (2x2), per-wave 64x64. Both operands gl16 (R4 proven).
// ---------------------------------------------------------------------------
__global__ __launch_bounds__(256, 1) void gemm_c_k(
    const unsigned short* __restrict__ hcat, const unsigned short* __restrict__ wc,
    const float* __restrict__ fc2_b, const float* __restrict__ mlp_out_b,
    const float* __restrict__ off_fc2_b, float* __restrict__ out) {
  __shared__ unsigned short As[2][128 * 32];
  __shared__ unsigned short Bs[2][128 * 32];
  const int tid = threadIdx.x, lane = tid & 63, w = tid >> 6;
  const int lid = swz(blockIdx.x, 6 * 394);
  const int by = lid / 6, bx = lid - by * 6;
  const int m0 = by * 128, n0 = bx * 128;

  const int srow = w * 32 + (lane >> 2), sc = (lane & 3) << 3;
  const unsigned short* gA = hcat + (size_t)(m0 + srow) * 576 + sc;
  const unsigned short* gB = wc + (size_t)(n0 + srow) * 576 + sc;
  auto stage = [&](int kt, int b) {
#pragma unroll
    for (int j = 0; j < 2; j++) {
      gl16(gA + kt * 32 + j * 16 * 576, &As[b][(srow + j * 16) * 32 + sc]);
      gl16(gB + kt * 32 + j * 16 * 576, &Bs[b][(srow + j * 16) * 32 + sc]);
    }
  };

  f32x4 acc[4][4];
#pragma unroll
  for (int i = 0; i < 4; i++)
#pragma unroll
    for (int j = 0; j < 4; j++) acc[i][j] = (f32x4){0.f, 0.f, 0.f, 0.f};

  const int fr = lane & 15, fq = lane >> 4;
  const int wm = (w >> 1) * 64, wn = (w & 1) * 64;

  stage(0, 0);
  __syncthreads();
  for (int kt = 0; kt < 18; ++kt) {
    const int b = kt & 1;
    if (kt + 1 < 18) stage(kt + 1, b ^ 1);
    s16x8 af[4], bfv[4];
#pragma unroll
    for (int mi = 0; mi < 4; mi++)
      af[mi] = *(const s16x8*)&As[b][(wm + mi * 16 + fr) * 32 + fq * 8];
#pragma unroll
    for (int ni = 0; ni < 4; ni++)
      bfv[ni] = *(const s16x8*)&Bs[b][(wn + ni * 16 + fr) * 32 + fq * 8];
#pragma unroll
    for (int mi = 0; mi < 4; mi++)
#pragma unroll
      for (int ni = 0; ni < 4; ni++) mfma16(acc[mi][ni], af[mi], bfv[ni]);
    __syncthreads();
  }

  float bv[4];
#pragma unroll
  for (int ni = 0; ni < 4; ni++) {
    const int c = n0 + wn + ni * 16 + fr;
    bv[ni] = fc2_b[c] + mlp_out_b[c] + (by >= 2 ? off_fc2_b[c] : 0.f);
  }
#pragma unroll
  for (int mi = 0; mi < 4; mi++)
#pragma unroll
    for (int r = 0; r < 4; r++) {
      const int m = m0 + wm + mi * 16 + fq * 4 + r;
      float* op = out + (size_t)m * C_DIM + n0 + wn;
#pragma unroll
      for (int ni = 0; ni < 4; ni++) op[ni * 16 + fr] = acc[mi][ni][r] + bv[ni];
    }
}

// ---------------------------------------------------------------------------
extern "C" void kernel_launch(void* const* d_in, const int* in_sizes, int n_in,
                              void* d_out, int out_size, void* d_ws, size_t ws_size,
                              hipStream_t stream) {
  const float* x          = (const float*)d_in[0];
  const float* fc1_w      = (const float*)d_in[2];
  const float* fc1_b      = (const float*)d_in[3];
  const float* conv_w     = (const float*)d_in[4];
  const float* conv_b     = (const float*)d_in[5];
  const float* fc2_w      = (const float*)d_in[6];
  const float* fc2_b      = (const float*)d_in[7];
  const float* off_fc1_w  = (const float*)d_in[8];
  const float* off_fc1_b  = (const float*)d_in[9];
  const float* off_conv_w = (const float*)d_in[10];
  const float* off_conv_b = (const float*)d_in[11];
  const float* off_fc2_w  = (const float*)d_in[12];
  const float* off_fc2_b  = (const float*)d_in[13];
  const float* mlp_in_w   = (const float*)d_in[14];
  const float* mlp_in_b   = (const float*)d_in[15];
  const float* mlp_out_w  = (const float*)d_in[16];
  const float* mlp_out_b  = (const float*)d_in[17];
  float* out = (float*)d_out;

  char* ws = (char*)d_ws;
  unsigned short* xb   = (unsigned short*)(ws);                       // 77.5 MB
  unsigned short* hcat = (unsigned short*)(ws + (size_t)M_DIM * C_DIM * 2);  // 58.1 MB
  unsigned short* wa   = (unsigned short*)(ws + (size_t)M_DIM * C_DIM * 2
                                              + (size_t)M_DIM * 576 * 2);
  unsigned short* wc   = wa + (size_t)576 * 768;

  prep_k<<<864, 256, 0, stream>>>(fc1_w, mlp_in_w, off_fc1_w, fc2_w, mlp_out_w,
                                  off_fc2_w, wa, wc);
  xcvt_k<<<2048, 256, 0, stream>>>(x, xb);
  gemm_a_k<<<1182, 256, 0, stream>>>(xb, wa, fc1_b, mlp_in_b, conv_w, conv_b,
                                     off_fc1_b, hcat);
  zfill_k<<<24, 256, 0, stream>>>(hcat);
  conv3d_k<<<1024, 256, 0, stream>>>(off_conv_w, off_conv_b, hcat);
  gemm_c_k<<<2364, 256, 0, stream>>>(hcat, wc, fc2_b, mlp_out_b, off_fc2_b, out);
}

// Round 9
// 217.030 us; speedup vs baseline: 1.1341x; 1.0118x over previous
//
#include <hip/hip_runtime.h>

// ---- problem constants ----
#define L_DIM 197
#define N_DIM 256
#define C_DIM 768
#define CA_DIM 192
#define M_DIM (L_DIM * N_DIM)   // 50432

typedef short s16x8 __attribute__((ext_vector_type(8)));
typedef float f32x4 __attribute__((ext_vector_type(4)));

__device__ __forceinline__ unsigned short f2bf(float f) {
  unsigned x = __builtin_bit_cast(unsigned, f);
  x = (x + 0x7fffu + ((x >> 16) & 1u)) >> 16;   // RNE
  return (unsigned short)x;
}
__device__ __forceinline__ float bflo(unsigned u) { return __builtin_bit_cast(float, u << 16); }
__device__ __forceinline__ float bfhi(unsigned u) { return __builtin_bit_cast(float, u & 0xffff0000u); }

__device__ __forceinline__ void unp8(uint4 v, float* f) {
  f[0] = bflo(v.x); f[1] = bfhi(v.x); f[2] = bflo(v.y); f[3] = bfhi(v.y);
  f[4] = bflo(v.z); f[5] = bfhi(v.z); f[6] = bflo(v.w); f[7] = bfhi(v.w);
}

__device__ __forceinline__ void mfma16(f32x4& acc, s16x8 a, s16x8 b) {
  asm("v_mfma_f32_16x16x32_bf16 %0, %1, %2, %0" : "+v"(acc) : "v"(a), "v"(b));
}

// async global->LDS 16B.  HW writes wave-uniform base + lane*16 — every call
// below is arranged so the per-lane LDS byte address == base + 16*lane.
typedef const void __attribute__((address_space(1)))* gp_t;
typedef void __attribute__((address_space(3)))* lp_t;
__device__ __forceinline__ void gl16(const void* g, void* l) {
  __builtin_amdgcn_global_load_lds((gp_t)g, (lp_t)l, 16, 0, 0);
}

// counted vmcnt: wait until at most N VMEM ops outstanding (keeps the N newest
// — i.e. next-tile prefetch — in flight across the barrier).  T4 lever.
#define WAITVM(n) asm volatile("s_waitcnt vmcnt(" #n ")" ::: "memory")

// bijective XCD-chunk swizzle (m204)
__device__ __forceinline__ int swz(int pid, int nwg) {
  const int q = nwg >> 3, r = nwg & 7, x = pid & 7, s = pid >> 3;
  return (x < r ? x * (q + 1) : r * (q + 1) + (x - r) * q) + s;
}

// ---------------------------------------------------------------------------
// prep: LDS-tiled transpose + fp32->bf16 of all six weight matrices.
// ---------------------------------------------------------------------------
__global__ __launch_bounds__(256) void prep_k(
    const float* __restrict__ fc1_w, const float* __restrict__ mlp_in_w,
    const float* __restrict__ off_fc1_w, const float* __restrict__ fc2_w,
    const float* __restrict__ mlp_out_w, const float* __restrict__ off_fc2_w,
    unsigned short* __restrict__ wa, unsigned short* __restrict__ wc) {
  __shared__ float t[32][33];
  const int b = blockIdx.x;              // 0..863
  const int job = b / 144, tt = b - job * 144;
  const float* in = job == 0 ? fc1_w : job == 1 ? mlp_in_w : job == 2 ? off_fc1_w
                  : job == 3 ? fc2_w : job == 4 ? mlp_out_w : off_fc2_w;
  const int Cc = job < 3 ? 192 : 768;
  const int tc = Cc >> 5;
  const int tr0 = (tt / tc) << 5, tc0 = (tt - (tt / tc) * tc) << 5;
  const int lr = threadIdx.x >> 5, lc = threadIdx.x & 31;
#pragma unroll
  for (int p = 0; p < 4; p++)
    t[p * 8 + lr][lc] = in[(tr0 + p * 8 + lr) * Cc + tc0 + lc];
  __syncthreads();
#pragma unroll
  for (int p = 0; p < 4; p++) {
    const int orow = tc0 + p * 8 + lr;
    const int ocol = tr0 + lc;
    const unsigned short v = f2bf(t[lc][p * 8 + lr]);
    if (job < 3) wa[(job * 192 + orow) * 768 + ocol] = v;
    else         wc[orow * 576 + (job - 3) * 192 + ocol] = v;
  }
}

// ---------------------------------------------------------------------------
// xcvt: x fp32 -> bf16, vectorized grid-stride.
// ---------------------------------------------------------------------------
__global__ __launch_bounds__(256) void xcvt_k(const float* __restrict__ x,
                                              unsigned short* __restrict__ xb) {
  const int total8 = M_DIM * C_DIM / 8;     // 4,841,472
  const int step = gridDim.x * 256;
  for (int i = blockIdx.x * 256 + threadIdx.x; i < total8; i += step) {
    const float4 a = *(const float4*)(x + (size_t)i * 8);
    const float4 b = *(const float4*)(x + (size_t)i * 8 + 4);
    s16x8 v;
    v[0] = (short)f2bf(a.x); v[1] = (short)f2bf(a.y);
    v[2] = (short)f2bf(a.z); v[3] = (short)f2bf(a.w);
    v[4] = (short)f2bf(b.x); v[5] = (short)f2bf(b.y);
    v[6] = (short)f2bf(b.z); v[7] = (short)f2bf(b.w);
    *(s16x8*)(xb + (size_t)i * 8) = v;
  }
}

// ---------------------------------------------------------------------------
// gemm_a: Y = xb(50432x768 bf16) @ wa-panel^T. BM=128, BN=192 (bx = path),
// BK=32, 256 threads = 4 waves (2m x 2n), per-wave 64x96 (24 MFMA/K-step).
// TRIPLE-buffered LDS, raw s_barrier, counted vmcnt(5): next-step loads stay
// in flight across the barrier (1 barrier / K-step, no drain).
// Fused epilogues:
//   bx0: conv1d over t (t = fq*4+r is fragment-local; 2 shuffles) -> hcat[0:192)
//   bx1: quickGELU(+mlp_in_b)                                     -> hcat[192:384)
//   bx2: temporal diff + off_fc1_b (rows l=0 -> 0)                -> hcat[384:576)
// ---------------------------------------------------------------------------
__global__ __launch_bounds__(256, 1) void gemm_a_k(
    const unsigned short* __restrict__ xb, const unsigned short* __restrict__ wa,
    const float* __restrict__ fc1_b, const float* __restrict__ mlp_in_b,
    const float* __restrict__ cw, const float* __restrict__ cb,
    const float* __restrict__ off_b1, unsigned short* __restrict__ hcat) {
  __shared__ unsigned short As[3][128 * 32];   // 3 x 8 KB
  __shared__ unsigned short Bs[3][192 * 32];   // 3 x 12 KB
  const int tid = threadIdx.x, lane = tid & 63, w = tid >> 6;
  const int lid = swz(blockIdx.x, 3 * 394);
  const int by = lid / 3, bx = lid - by * 3;
  const int m0 = by * 128, n0 = bx * 192;

  // staging: row sr = tid>>2, col sc = (tid&3)*8  ->  LDS byte = 16*tid
  const int sr = tid >> 2, sc = (tid & 3) * 8;
  const unsigned short* gA0 = xb + (size_t)(m0 + sr) * C_DIM + sc;        // rows 0-63
  const unsigned short* gA1 = xb + (size_t)(m0 + 64 + sr) * C_DIM + sc;   // rows 64-127
  const unsigned short* gB = wa + (size_t)(n0 + sr) * C_DIM + sc;

  auto stage = [&](int kt, int b) {           // 5 gl16 / thread
    gl16(gA0 + kt * 32, &As[b][sr * 32 + sc]);
    gl16(gA1 + kt * 32, &As[b][(64 + sr) * 32 + sc]);
    const unsigned short* pb = gB + kt * 32;
    gl16(pb,               &Bs[b][sr * 32 + sc]);
    gl16(pb + 64 * C_DIM,  &Bs[b][(64 + sr) * 32 + sc]);
    gl16(pb + 128 * C_DIM, &Bs[b][(128 + sr) * 32 + sc]);
  };

  f32x4 acc[4][6];
#pragma unroll
  for (int i = 0; i < 4; i++)
#pragma unroll
    for (int j = 0; j < 6; j++) acc[i][j] = (f32x4){0.f, 0.f, 0.f, 0.f};

  const int fr = lane & 15, fq = lane >> 4;
  const int wm = (w >> 1) * 64, wn = (w & 1) * 96;

  stage(0, 0);
#pragma unroll 3
  for (int kt = 0; kt < 24; ++kt) {
    const int b = kt % 3;
    if (kt + 1 < 24) { stage(kt + 1, (kt + 1) % 3); WAITVM(5); }
    else             { WAITVM(0); }
    __builtin_amdgcn_s_barrier();
    asm volatile("" ::: "memory");            // keep LDS reads below barrier
    s16x8 af[4], bfv[6];
#pragma unroll
    for (int mi = 0; mi < 4; mi++)
      af[mi] = *(const s16x8*)&As[b][(wm + mi * 16 + fr) * 32 + fq * 8];
#pragma unroll
    for (int ni = 0; ni < 6; ni++)
      bfv[ni] = *(const s16x8*)&Bs[b][(wn + ni * 16 + fr) * 32 + fq * 8];
#pragma unroll
    for (int mi = 0; mi < 4; mi++)
#pragma unroll
      for (int ni = 0; ni < 6; ni++) mfma16(acc[mi][ni], af[mi], bfv[ni]);
  }

  // ---- fused epilogues (t = fq*4 + r within each 16-row fragment) ----
  if (bx == 0) {
    // conv1d: out[t] = w0*h[t-1] + w1*h[t] + w2*h[t+1] + cb  (zero-padded)
#pragma unroll
    for (int ni = 0; ni < 6; ni++) {
      const int ca = wn + ni * 16 + fr;
      const float bv = fc1_b[ca];
      const float w0 = cw[ca * 3], w1 = cw[ca * 3 + 1], w2 = cw[ca * 3 + 2];
      const float cbv = cb[ca];
#pragma unroll
      for (int mi = 0; mi < 4; mi++) {
        const float v0 = acc[mi][ni][0] + bv, v1 = acc[mi][ni][1] + bv;
        const float v2 = acc[mi][ni][2] + bv, v3 = acc[mi][ni][3] + bv;
        const float pv3 = __shfl_up(v3, 16);    // h[t-1] when r==0 (from lane-16)
        const float nv0 = __shfl_down(v0, 16);  // h[t+1] when r==3 (from lane+16)
        const float p0 = fq > 0 ? pv3 : 0.f;
        const float n3 = fq < 3 ? nv0 : 0.f;
        const int mb = m0 + wm + mi * 16 + fq * 4;
        hcat[(size_t)(mb + 0) * 576 + ca] = f2bf(w0 * p0 + w1 * v0 + w2 * v1 + cbv);
        hcat[(size_t)(mb + 1) * 576 + ca] = f2bf(w0 * v0 + w1 * v1 + w2 * v2 + cbv);
        hcat[(size_t)(mb + 2) * 576 + ca] = f2bf(w0 * v1 + w1 * v2 + w2 * v3 + cbv);
        hcat[(size_t)(mb + 3) * 576 + ca] = f2bf(w0 * v2 + w1 * v3 + w2 * n3 + cbv);
      }
    }
  } else if (bx == 1) {
#pragma unroll
    for (int ni = 0; ni < 6; ni++) {
      const int ca = wn + ni * 16 + fr;
      const float bv = mlp_in_b[ca];
#pragma unroll
      for (int mi = 0; mi < 4; mi++)
#pragma unroll
        for (int r = 0; r < 4; r++) {
          const int m = m0 + wm + mi * 16 + fq * 4 + r;
          float v = acc[mi][ni][r] + bv;
          v = v / (1.f + __expf(-1.702f * v));   // quick_gelu
          hcat[(size_t)m * 576 + 192 + ca] = f2bf(v);
        }
    }
  } else {
    // temporal diff: d[t] = (t>0 ? y[t]-y[t-1] : 0) + off_fc1_b.
    // rows l==0 (by<2 <=> m<256) must be ZERO (offset branch excludes CLS row).
    const bool zrow = (by < 2);
#pragma unroll
    for (int ni = 0; ni < 6; ni++) {
      const int ca = wn + ni * 16 + fr;
      const float bv = off_b1[ca];
#pragma unroll
      for (int mi = 0; mi < 4; mi++) {
        const float v0 = acc[mi][ni][0], v1 = acc[mi][ni][1];
        const float v2 = acc[mi][ni][2], v3 = acc[mi][ni][3];
        const float pv3 = __shfl_up(v3, 16);
        const int mb = m0 + wm + mi * 16 + fq * 4;
        const float o0 = (fq == 0) ? bv : (v0 - pv3 + bv);   // t==0 iff fq==0 (r=0)
        if (zrow) {
          hcat[(size_t)(mb + 0) * 576 + 384 + ca] = 0;
          hcat[(size_t)(mb + 1) * 576 + 384 + ca] = 0;
          hcat[(size_t)(mb + 2) * 576 + 384 + ca] = 0;
          hcat[(size_t)(mb + 3) * 576 + 384 + ca] = 0;
        } else {
          hcat[(size_t)(mb + 0) * 576 + 384 + ca] = f2bf(o0);
          hcat[(size_t)(mb + 1) * 576 + 384 + ca] = f2bf(v1 - v0 + bv);
          hcat[(size_t)(mb + 2) * 576 + 384 + ca] = f2bf(v2 - v1 + bv);
          hcat[(size_t)(mb + 3) * 576 + 384 + ca] = f2bf(v3 - v2 + bv);
        }
      }
    }
  }
}

// ---------------------------------------------------------------------------
// conv3d: spatial-only 3x3 depthwise, IN-PLACE on hcat cols [384,576) rows
// l>=1. Block-local: one block per (frame n, channel quarter q) stages all of
// its rows into LDS, barriers, writes back. Temporal diff already applied.
// ---------------------------------------------------------------------------
__global__ __launch_bounds__(256) void conv3d_k(
    const float* __restrict__ w3, const float* __restrict__ b2,
    unsigned short* __restrict__ hcat) {
  __shared__ float ds[196 * 48];
  __shared__ float w3s[9 * 48];
  __shared__ float b2s[48];
  const int blk = blockIdx.x;           // 1024 = 256 frames x 4 quarters
  const int n = blk >> 2, q = blk & 3;
  const int ch0 = q * 48;
  const int tid = threadIdx.x;

  for (int j = tid; j < 432; j += 256) {
    const int c = j / 9, tap = j % 9;
    w3s[tap * 48 + c] = w3[(ch0 + c) * 9 + tap];
  }
  if (tid < 48) b2s[tid] = b2[ch0 + tid];

  for (int j = tid; j < 196 * 6; j += 256) {
    const int hw = j / 6, ck = j % 6;
    float dv[8];
    unp8(*(const uint4*)(hcat + ((size_t)(1 + hw) * 256 + n) * 576 + 384 + ch0 + ck * 8), dv);
#pragma unroll
    for (int e = 0; e < 8; e++) ds[hw * 48 + ck * 8 + e] = dv[e];
  }
  __syncthreads();

  for (int j = tid; j < 196 * 6; j += 256) {
    const int hw = j / 6, ck = j % 6;
    const int i = hw / 14, j0 = hw - i * 14;
    float acc[8];
#pragma unroll
    for (int e = 0; e < 8; e++) acc[e] = b2s[ck * 8 + e];
#pragma unroll
    for (int di = 0; di < 3; di++) {
      const int ii = i + di - 1;
      if (ii < 0 || ii >= 14) continue;
#pragma unroll
      for (int dj = 0; dj < 3; dj++) {
        const int jc = j0 + dj - 1;
        if (jc < 0 || jc >= 14) continue;
        const float* dp = &ds[(ii * 14 + jc) * 48 + ck * 8];
        const float* wp = &w3s[(di * 3 + dj) * 48 + ck * 8];
#pragma unroll
        for (int e = 0; e < 8; e++) acc[e] += wp[e] * dp[e];
      }
    }
    unsigned o[4];
#pragma unroll
    for (int e = 0; e < 8; e += 2)
      o[e / 2] = (unsigned)f2bf(acc[e]) | ((unsigned)f2bf(acc[e + 1]) << 16);
    uint4 ov; ov.x = o[0]; ov.y = o[1]; ov.z = o[2]; ov.w = o[3];
    *(uint4*)(hcat + ((size_t)(1 + hw) * 256 + n) * 576 + 384 + ch0 + ck * 8) = ov;
  }
}

// ---------------------------------------------------------------------------
// gemm_c: out = hcat(50432x576) @ wc^T + biases. BM=128, BN=128, BK=32,
// 256 threads = 4 waves (2x2), per-wave 64x64. Triple buffer + counted
// vmcnt(4) + raw barrier (same schedule as gemm_a).
// ---------------------------------------------------------------------------
__global__ __launch_bounds__(256, 1) void gemm_c_k(
    const unsigned short* __restrict__ hcat, const unsigned short* __restrict__ wc,
    const float* __restrict__ fc2_b, const float* __restrict__ mlp_out_b,
    const float* __restrict__ off_fc2_b, float* __restrict__ out) {
  __shared__ unsigned short As[3][128 * 32];
  __shared__ unsigned short Bs[3][128 * 32];
  const int tid = threadIdx.x, lane = tid & 63, w = tid >> 6;
  const int lid = swz(blockIdx.x, 6 * 394);
  const int by = lid / 6, bx = lid - by * 6;
  const int m0 = by * 128, n0 = bx * 128;

  const int srow = w * 32 + (lane >> 2), sc = (lane & 3) << 3;
  const unsigned short* gA = hcat + (size_t)(m0 + srow) * 576 + sc;
  const unsigned short* gB = wc + (size_t)(n0 + srow) * 576 + sc;
  auto stage = [&](int kt, int b) {           // 4 gl16 / thread
#pragma unroll
    for (int j = 0; j < 2; j++) {
      gl16(gA + kt * 32 + j * 16 * 576, &As[b][(srow + j * 16) * 32 + sc]);
      gl16(gB + kt * 32 + j * 16 * 576, &Bs[b][(srow + j * 16) * 32 + sc]);
    }
  };

  f32x4 acc[4][4];
#pragma unroll
  for (int i = 0; i < 4; i++)
#pragma unroll
    for (int j = 0; j < 4; j++) acc[i][j] = (f32x4){0.f, 0.f, 0.f, 0.f};

  const int fr = lane & 15, fq = lane >> 4;
  const int wm = (w >> 1) * 64, wn = (w & 1) * 64;

  stage(0, 0);
#pragma unroll 3
  for (int kt = 0; kt < 18; ++kt) {
    const int b = kt % 3;
    if (kt + 1 < 18) { stage(kt + 1, (kt + 1) % 3); WAITVM(4); }
    else             { WAITVM(0); }
    __builtin_amdgcn_s_barrier();
    asm volatile("" ::: "memory");
    s16x8 af[4], bfv[4];
#pragma unroll
    for (int mi = 0; mi < 4; mi++)
      af[mi] = *(const s16x8*)&As[b][(wm + mi * 16 + fr) * 32 + fq * 8];
#pragma unroll
    for (int ni = 0; ni < 4; ni++)
      bfv[ni] = *(const s16x8*)&Bs[b][(wn + ni * 16 + fr) * 32 + fq * 8];
#pragma unroll
    for (int mi = 0; mi < 4; mi++)
#pragma unroll
      for (int ni = 0; ni < 4; ni++) mfma16(acc[mi][ni], af[mi], bfv[ni]);
  }

  float bv[4];
#pragma unroll
  for (int ni = 0; ni < 4; ni++) {
    const int c = n0 + wn + ni * 16 + fr;
    bv[ni] = fc2_b[c] + mlp_out_b[c] + (by >= 2 ? off_fc2_b[c] : 0.f);
  }
#pragma unroll
  for (int mi = 0; mi < 4; mi++)
#pragma unroll
    for (int r = 0; r < 4; r++) {
      const int m = m0 + wm + mi * 16 + fq * 4 + r;
      float* op = out + (size_t)m * C_DIM + n0 + wn;
#pragma unroll
      for (int ni = 0; ni < 4; ni++) op[ni * 16 + fr] = acc[mi][ni][r] + bv[ni];
    }
}

// ---------------------------------------------------------------------------
extern "C" void kernel_launch(void* const* d_in, const int* in_sizes, int n_in,
                              void* d_out, int out_size, void* d_ws, size_t ws_size,
                              hipStream_t stream) {
  const float* x          = (const float*)d_in[0];
  const float* fc1_w      = (const float*)d_in[2];
  const float* fc1_b      = (const float*)d_in[3];
  const float* conv_w     = (const float*)d_in[4];
  const float* conv_b     = (const float*)d_in[5];
  const float* fc2_w      = (const float*)d_in[6];
  const float* fc2_b      = (const float*)d_in[7];
  const float* off_fc1_w  = (const float*)d_in[8];
  const float* off_fc1_b  = (const float*)d_in[9];
  const float* off_conv_w = (const float*)d_in[10];
  const float* off_conv_b = (const float*)d_in[11];
  const float* off_fc2_w  = (const float*)d_in[12];
  const float* off_fc2_b  = (const float*)d_in[13];
  const float* mlp_in_w   = (const float*)d_in[14];
  const float* mlp_in_b   = (const float*)d_in[15];
  const float* mlp_out_w  = (const float*)d_in[16];
  const float* mlp_out_b  = (const float*)d_in[17];
  float* out = (float*)d_out;

  char* ws = (char*)d_ws;
  unsigned short* xb   = (unsigned short*)(ws);                       // 77.5 MB
  unsigned short* hcat = (unsigned short*)(ws + (size_t)M_DIM * C_DIM * 2);  // 58.1 MB
  unsigned short* wa   = (unsigned short*)(ws + (size_t)M_DIM * C_DIM * 2
                                              + (size_t)M_DIM * 576 * 2);
  unsigned short* wc   = wa + (size_t)576 * 768;

  prep_k<<<864, 256, 0, stream>>>(fc1_w, mlp_in_w, off_fc1_w, fc2_w, mlp_out_w,
                                  off_fc2_w, wa, wc);
  xcvt_k<<<2048, 256, 0, stream>>>(x, xb);
  gemm_a_k<<<1182, 256, 0, stream>>>(xb, wa, fc1_b, mlp_in_b, conv_w, conv_b,
                                     off_fc1_b, hcat);
  conv3d_k<<<1024, 256, 0, stream>>>(off_conv_w, off_conv_b, hcat);
  gemm_c_k<<<2364, 256, 0, stream>>>(hcat, wc, fc2_b, mlp_out_b, off_fc2_b, out);
}

// Round 10
// 204.115 us; speedup vs baseline: 1.2058x; 1.0633x over previous
//
#include <hip/hip_runtime.h>

// ---- problem constants ----
#define L_DIM 197
#define N_DIM 256
#define C_DIM 768
#define CA_DIM 192
#define M_DIM (L_DIM * N_DIM)   // 50432

typedef short s16x8 __attribute__((ext_vector_type(8)));
typedef float f32x4 __attribute__((ext_vector_type(4)));

__device__ __forceinline__ unsigned short f2bf(float f) {
  unsigned x = __builtin_bit_cast(unsigned, f);
  x = (x + 0x7fffu + ((x >> 16) & 1u)) >> 16;   // RNE
  return (unsigned short)x;
}
__device__ __forceinline__ float bflo(unsigned u) { return __builtin_bit_cast(float, u << 16); }
__device__ __forceinline__ float bfhi(unsigned u) { return __builtin_bit_cast(float, u & 0xffff0000u); }

__device__ __forceinline__ void unp8(uint4 v, float* f) {
  f[0] = bflo(v.x); f[1] = bfhi(v.x); f[2] = bflo(v.y); f[3] = bfhi(v.y);
  f[4] = bflo(v.z); f[5] = bfhi(v.z); f[6] = bflo(v.w); f[7] = bfhi(v.w);
}

// packed fp32x2 -> bf16x2 (RNE), single VALU op
__device__ __forceinline__ unsigned cvtpk(float lo, float hi) {
  unsigned r;
  asm("v_cvt_pk_bf16_f32 %0, %1, %2" : "=v"(r) : "v"(lo), "v"(hi));
  return r;
}

__device__ __forceinline__ void mfma16(f32x4& acc, s16x8 a, s16x8 b) {
  asm("v_mfma_f32_16x16x32_bf16 %0, %1, %2, %0" : "+v"(acc) : "v"(a), "v"(b));
}

// async global->LDS 16B.  HW writes wave-uniform base + lane*16 — every call
// below is arranged so the per-lane LDS byte address == base + 16*lane.
typedef const void __attribute__((address_space(1)))* gp_t;
typedef void __attribute__((address_space(3)))* lp_t;
__device__ __forceinline__ void gl16(const void* g, void* l) {
  __builtin_amdgcn_global_load_lds((gp_t)g, (lp_t)l, 16, 0, 0);
}

// counted vmcnt (T4): keep the N newest VMEM ops in flight across the barrier.
#define WAITVM(n) asm volatile("s_waitcnt vmcnt(" #n ")" ::: "memory")
// barrier that also makes ds_write staging visible
#define BARRIER_LG() asm volatile("s_waitcnt lgkmcnt(0)\ns_barrier" ::: "memory")

// bijective XCD-chunk swizzle (m204)
__device__ __forceinline__ int swz(int pid, int nwg) {
  const int q = nwg >> 3, r = nwg & 7, x = pid & 7, s = pid >> 3;
  return (x < r ? x * (q + 1) : r * (q + 1) + (x - r) * q) + s;
}

// ---------------------------------------------------------------------------
// prep: LDS-tiled transpose + fp32->bf16 of all six weight matrices.
// ---------------------------------------------------------------------------
__global__ __launch_bounds__(256) void prep_k(
    const float* __restrict__ fc1_w, const float* __restrict__ mlp_in_w,
    const float* __restrict__ off_fc1_w, const float* __restrict__ fc2_w,
    const float* __restrict__ mlp_out_w, const float* __restrict__ off_fc2_w,
    unsigned short* __restrict__ wa, unsigned short* __restrict__ wc) {
  __shared__ float t[32][33];
  const int b = blockIdx.x;              // 0..863
  const int job = b / 144, tt = b - job * 144;
  const float* in = job == 0 ? fc1_w : job == 1 ? mlp_in_w : job == 2 ? off_fc1_w
                  : job == 3 ? fc2_w : job == 4 ? mlp_out_w : off_fc2_w;
  const int Cc = job < 3 ? 192 : 768;
  const int tc = Cc >> 5;
  const int tr0 = (tt / tc) << 5, tc0 = (tt - (tt / tc) * tc) << 5;
  const int lr = threadIdx.x >> 5, lc = threadIdx.x & 31;
#pragma unroll
  for (int p = 0; p < 4; p++)
    t[p * 8 + lr][lc] = in[(tr0 + p * 8 + lr) * Cc + tc0 + lc];
  __syncthreads();
#pragma unroll
  for (int p = 0; p < 4; p++) {
    const int orow = tc0 + p * 8 + lr;
    const int ocol = tr0 + lc;
    const unsigned short v = f2bf(t[lc][p * 8 + lr]);
    if (job < 3) wa[(job * 192 + orow) * 768 + ocol] = v;
    else         wc[orow * 576 + (job - 3) * 192 + ocol] = v;
  }
}

// ---------------------------------------------------------------------------
// gemm_a: Y = x(50432x768 fp32) @ wa-panel^T.  BM=128, BN=192 (bx = path),
// BK=32, 256 threads = 4 waves (2m x 2n), per-wave 64x96 (24 MFMA/K-step).
// A: fp32 float4 loads issued ONE K-STEP EARLY (double reg set), cvt_pk ->
// ds_write into triple-buffered LDS.  B: global_load_lds.  Counted vmcnt:
// per iter issue ldA(kt+2)[4] + stB(kt+1)[3]; WAITVM(7) retires exactly
// ldA(kt+1)+stB(kt).  Barrier carries lgkmcnt(0) for the ds_writes.
// Fused epilogues:
//   bx0: conv1d over t (t = fq*4+r fragment-local; 2 shuffles) -> hcat[0:192)
//   bx1: quickGELU(+mlp_in_b)                                  -> hcat[192:384)
//   bx2: temporal diff + off_fc1_b (rows l=0 -> 0)             -> hcat[384:576)
// ---------------------------------------------------------------------------
__global__ __launch_bounds__(256, 1) void gemm_a_k(
    const float* __restrict__ x, const unsigned short* __restrict__ wa,
    const float* __restrict__ fc1_b, const float* __restrict__ mlp_in_b,
    const float* __restrict__ cw, const float* __restrict__ cb,
    const float* __restrict__ off_b1, unsigned short* __restrict__ hcat) {
  __shared__ unsigned short As[3][128 * 32];   // 3 x 8 KB
  __shared__ unsigned short Bs[3][192 * 32];   // 3 x 12 KB
  const int tid = threadIdx.x, lane = tid & 63, w = tid >> 6;
  const int lid = swz(blockIdx.x, 3 * 394);
  const int by = lid / 3, bx = lid - by * 3;
  const int m0 = by * 128, n0 = bx * 192;

  // staging geometry: row sr = tid>>2 (0..63), 8-elem col chunk sc8 = (tid&3)*8
  const int sr = tid >> 2, sc8 = (tid & 3) * 8;
  const float* gA = x + (size_t)(m0 + sr) * C_DIM + sc8;          // + row 64 variant
  const unsigned short* gB = wa + (size_t)(n0 + sr) * C_DIM + sc8;

  float4 avA[4], avB[4];   // two reg sets (parity kt&1), each: rows {sr, sr+64} x 8 fp32
  auto ldA = [&](int kt, float4* av) {
    const float* p = gA + kt * 32;
    av[0] = *(const float4*)p;                  av[1] = *(const float4*)(p + 4);
    av[2] = *(const float4*)(p + 64 * C_DIM);   av[3] = *(const float4*)(p + 64 * C_DIM + 4);
  };
  auto wrA = [&](int b, const float4* av) {
    uint4 u0, u1;
    u0.x = cvtpk(av[0].x, av[0].y); u0.y = cvtpk(av[0].z, av[0].w);
    u0.z = cvtpk(av[1].x, av[1].y); u0.w = cvtpk(av[1].z, av[1].w);
    u1.x = cvtpk(av[2].x, av[2].y); u1.y = cvtpk(av[2].z, av[2].w);
    u1.z = cvtpk(av[3].x, av[3].y); u1.w = cvtpk(av[3].z, av[3].w);
    *(uint4*)&As[b][sr * 32 + sc8] = u0;
    *(uint4*)&As[b][(64 + sr) * 32 + sc8] = u1;
  };
  auto stB = [&](int kt, int b) {              // 3 gl16 / thread
    const unsigned short* pb = gB + kt * 32;
    gl16(pb,               &Bs[b][sr * 32 + sc8]);
    gl16(pb + 64 * C_DIM,  &Bs[b][(64 + sr) * 32 + sc8]);
    gl16(pb + 128 * C_DIM, &Bs[b][(128 + sr) * 32 + sc8]);
  };

  f32x4 acc[4][6];
#pragma unroll
  for (int i = 0; i < 4; i++)
#pragma unroll
    for (int j = 0; j < 6; j++) acc[i][j] = (f32x4){0.f, 0.f, 0.f, 0.f};

  const int fr = lane & 15, fq = lane >> 4;
  const int wm = (w >> 1) * 64, wn = (w & 1) * 96;

  // prologue: ldA(0)->setA, stB(0), ldA(1)->setB; wait ldA(0); write As[0]
  ldA(0, avA);
  stB(0, 0);
  ldA(1, avB);
  WAITVM(7);
  wrA(0, avA);

#pragma unroll 6
  for (int kt = 0; kt < 24; ++kt) {
    const int b = kt % 3;
    float4* ldset = ((kt & 1) == 0) ? avA : avB;   // fills set kt&1 ( = (kt+2)&1 )
    float4* wrset = ((kt & 1) == 0) ? avB : avA;   // uses set (kt+1)&1
    if (kt + 2 < 24) ldA(kt + 2, ldset);
    if (kt + 1 < 24) stB(kt + 1, (kt + 1) % 3);
    if (kt < 22)      { WAITVM(7); }
    else if (kt == 22){ WAITVM(3); }
    else              { WAITVM(0); }
    if (kt + 1 < 24) wrA((kt + 1) % 3, wrset);
    BARRIER_LG();
    s16x8 af[4], bfv[6];
#pragma unroll
    for (int mi = 0; mi < 4; mi++)
      af[mi] = *(const s16x8*)&As[b][(wm + mi * 16 + fr) * 32 + fq * 8];
#pragma unroll
    for (int ni = 0; ni < 6; ni++)
      bfv[ni] = *(const s16x8*)&Bs[b][(wn + ni * 16 + fr) * 32 + fq * 8];
#pragma unroll
    for (int mi = 0; mi < 4; mi++)
#pragma unroll
      for (int ni = 0; ni < 6; ni++) mfma16(acc[mi][ni], af[mi], bfv[ni]);
  }

  // ---- fused epilogues (t = fq*4 + r within each 16-row fragment) ----
  if (bx == 0) {
#pragma unroll
    for (int ni = 0; ni < 6; ni++) {
      const int ca = wn + ni * 16 + fr;
      const float bv = fc1_b[ca];
      const float w0 = cw[ca * 3], w1 = cw[ca * 3 + 1], w2 = cw[ca * 3 + 2];
      const float cbv = cb[ca];
#pragma unroll
      for (int mi = 0; mi < 4; mi++) {
        const float v0 = acc[mi][ni][0] + bv, v1 = acc[mi][ni][1] + bv;
        const float v2 = acc[mi][ni][2] + bv, v3 = acc[mi][ni][3] + bv;
        const float pv3 = __shfl_up(v3, 16);    // h[t-1] when r==0 (from lane-16)
        const float nv0 = __shfl_down(v0, 16);  // h[t+1] when r==3 (from lane+16)
        const float p0 = fq > 0 ? pv3 : 0.f;
        const float n3 = fq < 3 ? nv0 : 0.f;
        const int mb = m0 + wm + mi * 16 + fq * 4;
        hcat[(size_t)(mb + 0) * 576 + ca] = f2bf(w0 * p0 + w1 * v0 + w2 * v1 + cbv);
        hcat[(size_t)(mb + 1) * 576 + ca] = f2bf(w0 * v0 + w1 * v1 + w2 * v2 + cbv);
        hcat[(size_t)(mb + 2) * 576 + ca] = f2bf(w0 * v1 + w1 * v2 + w2 * v3 + cbv);
        hcat[(size_t)(mb + 3) * 576 + ca] = f2bf(w0 * v2 + w1 * v3 + w2 * n3 + cbv);
      }
    }
  } else if (bx == 1) {
#pragma unroll
    for (int ni = 0; ni < 6; ni++) {
      const int ca = wn + ni * 16 + fr;
      const float bv = mlp_in_b[ca];
#pragma unroll
      for (int mi = 0; mi < 4; mi++)
#pragma unroll
        for (int r = 0; r < 4; r++) {
          const int m = m0 + wm + mi * 16 + fq * 4 + r;
          float v = acc[mi][ni][r] + bv;
          v = v / (1.f + __expf(-1.702f * v));   // quick_gelu
          hcat[(size_t)m * 576 + 192 + ca] = f2bf(v);
        }
    }
  } else {
    const bool zrow = (by < 2);                  // rows l==0 (m<256) -> 0
#pragma unroll
    for (int ni = 0; ni < 6; ni++) {
      const int ca = wn + ni * 16 + fr;
      const float bv = off_b1[ca];
#pragma unroll
      for (int mi = 0; mi < 4; mi++) {
        const float v0 = acc[mi][ni][0], v1 = acc[mi][ni][1];
        const float v2 = acc[mi][ni][2], v3 = acc[mi][ni][3];
        const float pv3 = __shfl_up(v3, 16);
        const int mb = m0 + wm + mi * 16 + fq * 4;
        const float o0 = (fq == 0) ? bv : (v0 - pv3 + bv);
        if (zrow) {
          hcat[(size_t)(mb + 0) * 576 + 384 + ca] = 0;
          hcat[(size_t)(mb + 1) * 576 + 384 + ca] = 0;
          hcat[(size_t)(mb + 2) * 576 + 384 + ca] = 0;
          hcat[(size_t)(mb + 3) * 576 + 384 + ca] = 0;
        } else {
          hcat[(size_t)(mb + 0) * 576 + 384 + ca] = f2bf(o0);
          hcat[(size_t)(mb + 1) * 576 + 384 + ca] = f2bf(v1 - v0 + bv);
          hcat[(size_t)(mb + 2) * 576 + 384 + ca] = f2bf(v2 - v1 + bv);
          hcat[(size_t)(mb + 3) * 576 + 384 + ca] = f2bf(v3 - v2 + bv);
        }
      }
    }
  }
}

// ---------------------------------------------------------------------------
// conv3d: spatial-only 3x3 depthwise, IN-PLACE on hcat cols [384,576) rows
// l>=1. One block per (frame n, channel quarter q); temporal diff already done.
// ---------------------------------------------------------------------------
__global__ __launch_bounds__(256) void conv3d_k(
    const float* __restrict__ w3, const float* __restrict__ b2,
    unsigned short* __restrict__ hcat) {
  __shared__ float ds[196 * 48];
  __shared__ float w3s[9 * 48];
  __shared__ float b2s[48];
  const int blk = blockIdx.x;           // 1024 = 256 frames x 4 quarters
  const int n = blk >> 2, q = blk & 3;
  const int ch0 = q * 48;
  const int tid = threadIdx.x;

  for (int j = tid; j < 432; j += 256) {
    const int c = j / 9, tap = j % 9;
    w3s[tap * 48 + c] = w3[(ch0 + c) * 9 + tap];
  }
  if (tid < 48) b2s[tid] = b2[ch0 + tid];

  for (int j = tid; j < 196 * 6; j += 256) {
    const int hw = j / 6, ck = j % 6;
    float dv[8];
    unp8(*(const uint4*)(hcat + ((size_t)(1 + hw) * 256 + n) * 576 + 384 + ch0 + ck * 8), dv);
#pragma unroll
    for (int e = 0; e < 8; e++) ds[hw * 48 + ck * 8 + e] = dv[e];
  }
  __syncthreads();

  for (int j = tid; j < 196 * 6; j += 256) {
    const int hw = j / 6, ck = j % 6;
    const int i = hw / 14, j0 = hw - i * 14;
    float acc[8];
#pragma unroll
    for (int e = 0; e < 8; e++) acc[e] = b2s[ck * 8 + e];
#pragma unroll
    for (int di = 0; di < 3; di++) {
      const int ii = i + di - 1;
      if (ii < 0 || ii >= 14) continue;
#pragma unroll
      for (int dj = 0; dj < 3; dj++) {
        const int jc = j0 + dj - 1;
        if (jc < 0 || jc >= 14) continue;
        const float* dp = &ds[(ii * 14 + jc) * 48 + ck * 8];
        const float* wp = &w3s[(di * 3 + dj) * 48 + ck * 8];
#pragma unroll
        for (int e = 0; e < 8; e++) acc[e] += wp[e] * dp[e];
      }
    }
    unsigned o[4];
#pragma unroll
    for (int e = 0; e < 8; e += 2)
      o[e / 2] = (unsigned)f2bf(acc[e]) | ((unsigned)f2bf(acc[e + 1]) << 16);
    uint4 ov; ov.x = o[0]; ov.y = o[1]; ov.z = o[2]; ov.w = o[3];
    *(uint4*)(hcat + ((size_t)(1 + hw) * 256 + n) * 576 + 384 + ch0 + ck * 8) = ov;
  }
}

// ---------------------------------------------------------------------------
// gemm_c: out = hcat(50432x576) @ wc^T + biases.  BM=128, BN=256, BK=32,
// 256 threads = 4 waves (2m x 2n), per-wave 64x128 -> acc[4][8]
// (32 MFMA per 12 ds_read — ratio 2.67 vs old 2.0).  Triple buffer +
// counted vmcnt(6) + raw barrier (R9-proven schedule).
// ---------------------------------------------------------------------------
__global__ __launch_bounds__(256, 1) void gemm_c_k(
    const unsigned short* __restrict__ hcat, const unsigned short* __restrict__ wc,
    const float* __restrict__ fc2_b, const float* __restrict__ mlp_out_b,
    const float* __restrict__ off_fc2_b, float* __restrict__ out) {
  __shared__ unsigned short As[3][128 * 32];   // 3 x 8 KB
  __shared__ unsigned short Bs[3][256 * 32];   // 3 x 16 KB
  const int tid = threadIdx.x, lane = tid & 63, w = tid >> 6;
  const int lid = swz(blockIdx.x, 3 * 394);
  const int by = lid / 3, bx = lid - by * 3;
  const int m0 = by * 128, n0 = bx * 256;

  const int sr = tid >> 2, sc = (tid & 3) * 8;      // row 0..63, col chunk
  const unsigned short* gA = hcat + (size_t)(m0 + sr) * 576 + sc;
  const unsigned short* gB = wc + (size_t)(n0 + sr) * 576 + sc;
  auto stage = [&](int kt, int b) {            // 6 gl16 / thread
#pragma unroll
    for (int j = 0; j < 2; j++)
      gl16(gA + kt * 32 + j * 64 * 576, &As[b][(sr + j * 64) * 32 + sc]);
#pragma unroll
    for (int j = 0; j < 4; j++)
      gl16(gB + kt * 32 + j * 64 * 576, &Bs[b][(sr + j * 64) * 32 + sc]);
  };

  f32x4 acc[4][8];
#pragma unroll
  for (int i = 0; i < 4; i++)
#pragma unroll
    for (int j = 0; j < 8; j++) acc[i][j] = (f32x4){0.f, 0.f, 0.f, 0.f};

  const int fr = lane & 15, fq = lane >> 4;
  const int wm = (w >> 1) * 64, wn = (w & 1) * 128;

  stage(0, 0);
#pragma unroll 3
  for (int kt = 0; kt < 18; ++kt) {
    const int b = kt % 3;
    if (kt + 1 < 18) { stage(kt + 1, (kt + 1) % 3); WAITVM(6); }
    else             { WAITVM(0); }
    __builtin_amdgcn_s_barrier();
    asm volatile("" ::: "memory");
    s16x8 af[4], bfv[8];
#pragma unroll
    for (int mi = 0; mi < 4; mi++)
      af[mi] = *(const s16x8*)&As[b][(wm + mi * 16 + fr) * 32 + fq * 8];
#pragma unroll
    for (int ni = 0; ni < 8; ni++)
      bfv[ni] = *(const s16x8*)&Bs[b][(wn + ni * 16 + fr) * 32 + fq * 8];
#pragma unroll
    for (int mi = 0; mi < 4; mi++)
#pragma unroll
      for (int ni = 0; ni < 8; ni++) mfma16(acc[mi][ni], af[mi], bfv[ni]);
  }

  float bv[8];
#pragma unroll
  for (int ni = 0; ni < 8; ni++) {
    const int c = n0 + wn + ni * 16 + fr;
    bv[ni] = fc2_b[c] + mlp_out_b[c] + (by >= 2 ? off_fc2_b[c] : 0.f);
  }
#pragma unroll
  for (int mi = 0; mi < 4; mi++)
#pragma unroll
    for (int r = 0; r < 4; r++) {
      const int m = m0 + wm + mi * 16 + fq * 4 + r;
      float* op = out + (size_t)m * C_DIM + n0 + wn;
#pragma unroll
      for (int ni = 0; ni < 8; ni++) op[ni * 16 + fr] = acc[mi][ni][r] + bv[ni];
    }
}

// ---------------------------------------------------------------------------
extern "C" void kernel_launch(void* const* d_in, const int* in_sizes, int n_in,
                              void* d_out, int out_size, void* d_ws, size_t ws_size,
                              hipStream_t stream) {
  const float* x          = (const float*)d_in[0];
  const float* fc1_w      = (const float*)d_in[2];
  const float* fc1_b      = (const float*)d_in[3];
  const float* conv_w     = (const float*)d_in[4];
  const float* conv_b     = (const float*)d_in[5];
  const float* fc2_w      = (const float*)d_in[6];
  const float* fc2_b      = (const float*)d_in[7];
  const float* off_fc1_w  = (const float*)d_in[8];
  const float* off_fc1_b  = (const float*)d_in[9];
  const float* off_conv_w = (const float*)d_in[10];
  const float* off_conv_b = (const float*)d_in[11];
  const float* off_fc2_w  = (const float*)d_in[12];
  const float* off_fc2_b  = (const float*)d_in[13];
  const float* mlp_in_w   = (const float*)d_in[14];
  const float* mlp_in_b   = (const float*)d_in[15];
  const float* mlp_out_w  = (const float*)d_in[16];
  const float* mlp_out_b  = (const float*)d_in[17];
  float* out = (float*)d_out;

  char* ws = (char*)d_ws;
  unsigned short* hcat = (unsigned short*)(ws);                     // 58.1 MB
  unsigned short* wa   = (unsigned short*)(ws + (size_t)M_DIM * 576 * 2);
  unsigned short* wc   = wa + (size_t)576 * 768;

  prep_k<<<864, 256, 0, stream>>>(fc1_w, mlp_in_w, off_fc1_w, fc2_w, mlp_out_w,
                                  off_fc2_w, wa, wc);
  gemm_a_k<<<1182, 256, 0, stream>>>(x, wa, fc1_b, mlp_in_b, conv_w, conv_b,
                                     off_fc1_b, hcat);
  conv3d_k<<<1024, 256, 0, stream>>>(off_conv_w, off_conv_b, hcat);
  gemm_c_k<<<1182, 256, 0, stream>>>(hcat, wc, fc2_b, mlp_out_b, off_fc2_b, out);
}